// Round 1
// 12791.221 us; speedup vs baseline: 1.2156x; 1.2156x over previous
//
#include <hip/hip_runtime.h>
#include <stdint.h>

// ---------------------------------------------------------------------------
// RnnInferenceNetwork: GRU-variant scan, T=1024, SB=256 rows, H=512, L=64.
// Design: 128 persistent wgs (8 row-blocks x 16 col-groups), weights resident
// in LDS (W_h/W_xz slices) + VGPRs (W_d frags), h/u state exchanged via LLC.
// x@W_x precomputed (bf16 MFMA).
// R2 fixes: (1) phase-2 n-preact includes z_prev@W_x[D:,2H:]; (2) fp32
// register carry of own h tile; (3) raw/z-gate fp32 in LDS.
// R3: communication is block-diagonal (row-block r only reads its own 16
// slices) -> replace the 128-WG centralized counter barrier with per-row-block
// 16-WG flag-array barriers (no atomic RMW serialization, no cross-row-block
// straggler coupling). Each WG publishes a monotone phase counter to its own
// slot; wave 0 polls the 16 slots; one agent-acquire fence before reload.
// ---------------------------------------------------------------------------

#define NWG  128u

typedef __bf16 bf16;
typedef __attribute__((ext_vector_type(8))) __bf16 bf16x8;
typedef __attribute__((ext_vector_type(8))) short  s16x8;
typedef __attribute__((ext_vector_type(4))) float  f32x4;
typedef __attribute__((ext_vector_type(4))) unsigned int u32x4;

__device__ __forceinline__ f32x4 mfma16(bf16x8 a, bf16x8 b, f32x4 c) {
  return __builtin_amdgcn_mfma_f32_16x16x32_bf16(
      __builtin_bit_cast(s16x8, a), __builtin_bit_cast(s16x8, b), c, 0, 0, 0);
}

// --------------------------- repack weights --------------------------------
// B-fragment layout: [kc][q][n][j] ; element = W[k = kc*32+q*8+j][col(n)]
// Whs: [c16][kc16][q4][n96][j8]   col = (n/32)*512 + 32c + (n%32)   (W_h)
// Wxz: [c16][kc2 ][q4][n96][j8]   same col, rows 256..319 of W_x
// Wdf: [kc16][q4][n128][j8]       col = n                            (W_d)
// Wxx: [c16][kc8 ][q4][n96][j8]   same col, rows 0..255 of W_x
__global__ void repack_kernel(const float* __restrict__ W_x,
                              const float* __restrict__ W_h,
                              const float* __restrict__ W_d,
                              bf16* __restrict__ Whs, bf16* __restrict__ Wxz,
                              bf16* __restrict__ Wdf, bf16* __restrict__ Wxx)
{
  unsigned e = blockIdx.x*256u + threadIdx.x;
  if (e < 786432u) {
    unsigned c = e/49152u, r0 = e%49152u;
    unsigned kc = r0/3072u, r1 = r0%3072u;
    unsigned q = r1/768u, r2 = r1%768u;
    unsigned n = r2/8u, j = r2%8u;
    unsigned k = kc*32u + q*8u + j;
    unsigned colg = (n>>5)*512u + c*32u + (n&31u);
    Whs[e] = (bf16)W_h[k*1536u + colg];
  } else if (e < 884736u) {
    unsigned e1 = e - 786432u;
    unsigned c = e1/6144u, r0 = e1%6144u;
    unsigned kc = r0/3072u, r1 = r0%3072u;
    unsigned q = r1/768u, r2 = r1%768u;
    unsigned n = r2/8u, j = r2%8u;
    unsigned k = 256u + kc*32u + q*8u + j;
    unsigned colg = (n>>5)*512u + c*32u + (n&31u);
    Wxz[e1] = (bf16)W_x[k*1536u + colg];
  } else if (e < 950272u) {
    unsigned e2 = e - 884736u;
    unsigned kc = e2/4096u, r0 = e2%4096u;
    unsigned q = r0/1024u, r1 = r0%1024u;
    unsigned n = r1/8u, j = r1%8u;
    unsigned k = kc*32u + q*8u + j;
    Wdf[e2] = (bf16)W_d[k*128u + n];
  } else if (e < 1343488u) {
    unsigned e3 = e - 950272u;
    unsigned c = e3/24576u, r0 = e3%24576u;
    unsigned kc = r0/3072u, r1 = r0%3072u;
    unsigned q = r1/768u, r2 = r1%768u;
    unsigned n = r2/8u, j = r2%8u;
    unsigned k = kc*32u + q*8u + j;
    unsigned colg = (n>>5)*512u + c*32u + (n&31u);
    Wxx[e3] = (bf16)W_x[k*1536u + colg];
  }
}

// ----------------- transpose x [B][T][D] f32 -> xT [t][b][d] bf16 ----------
__global__ void xpose_kernel(const float* __restrict__ x, bf16* __restrict__ xT)
{
  unsigned t = blockIdx.x, tid = threadIdx.x;
  unsigned row = tid>>2, seg = tid&3u;
  const float* src = x + ((size_t)row*1024u + t)*256u + seg*64u;
  bf16* dst = xT + (size_t)t*16384u + row*256u + seg*64u;
  #pragma unroll
  for (int i = 0; i < 8; ++i) {
    f32x4 v0 = *(const f32x4*)(src + i*8);
    f32x4 v1 = *(const f32x4*)(src + i*8 + 4);
    bf16x8 o;
    #pragma unroll
    for (int j = 0; j < 4; ++j) { o[j] = (bf16)v0[j]; o[4+j] = (bf16)v1[j]; }
    *(bf16x8*)(dst + i*8) = o;
  }
}

// --------- xg_x precompute: xgx[lt][c][b64][n96] = x@W_x[:256]+b (bf16) ----
__global__ void __launch_bounds__(256) xgx_kernel(const bf16* __restrict__ xT,
                                                  const bf16* __restrict__ Wxx,
                                                  const float* __restrict__ bias,
                                                  bf16* __restrict__ xgx,
                                                  unsigned t0)
{
  __shared__ bf16 WxS[24576];
  __shared__ bf16 otile[6144];
  unsigned bid = blockIdx.x, lt = bid>>4, c = bid&15u, tid = threadIdx.x;
  unsigned t = t0 + lt;
  { const u32x4* s = (const u32x4*)(Wxx + (size_t)c*24576u); u32x4* d = (u32x4*)WxS;
    #pragma unroll
    for (int i=0;i<12;i++) d[tid+256u*i] = s[tid+256u*i]; }
  __syncthreads();
  unsigned wave = tid>>6, lane = tid&63u, q = lane>>4, m = lane&15u;
  f32x4 zero4 = {0.f,0.f,0.f,0.f};
  f32x4 acc[6];
  #pragma unroll
  for (int nt=0;nt<6;nt++) acc[nt] = zero4;
  const bf16* ap = xT + (size_t)t*16384u + (16u*wave + m)*256u + q*8u;
  #pragma unroll
  for (int kc=0;kc<8;kc++) {
    bf16x8 a = *(const bf16x8*)(ap + kc*32);
    #pragma unroll
    for (int nt=0;nt<6;nt++) {
      bf16x8 bb = *(const bf16x8*)(WxS + (((unsigned)kc*4u+q)*96u + (unsigned)nt*16u + m)*8u);
      acc[nt] = mfma16(a, bb, acc[nt]);
    }
  }
  #pragma unroll
  for (int nt=0;nt<6;nt++) {
    unsigned n = (unsigned)nt*16u + m;
    unsigned colg = (n>>5)*512u + c*32u + (n&31u);
    float bv = bias[colg];
    #pragma unroll
    for (int reg=0;reg<4;reg++)
      otile[(16u*wave + 4u*q + (unsigned)reg)*96u + n] = (bf16)(acc[nt][reg] + bv);
  }
  __syncthreads();
  { u32x4* d = (u32x4*)(xgx + (size_t)(lt*16u + c)*6144u);
    const u32x4* s = (const u32x4*)otile;
    #pragma unroll
    for (int i=0;i<3;i++) d[tid+256u*i] = s[tid+256u*i]; }
}

// ------------------- per-row-block barrier (16 WGs) ------------------------
// flags: 16 u32 slots on one 256-B region, one per col-group. Each WG
// publishes the monotone phase counter `target` to its own slot after its
// agent-scope data stores are drained (vmcnt(0) at __syncthreads). Wave 0
// polls all 16 slots with relaxed agent loads (bypass L1/L2 -> LLC), then a
// single agent-acquire fence invalidates stale L1/L2 lines before the data
// reload. No atomic RMW, no coupling across row-blocks.
__device__ __forceinline__ void rb_barrier(unsigned* __restrict__ flags,
                                           unsigned tid, unsigned lane,
                                           unsigned wave, unsigned c,
                                           unsigned target)
{
  __syncthreads();   // drains vmcnt -> all this-WG stores visible at LLC
  if (tid == 0)
    __hip_atomic_store(&flags[c], target, __ATOMIC_RELAXED,
                       __HIP_MEMORY_SCOPE_AGENT);
  if (wave == 0) {
    for (;;) {
      unsigned v = target;
      if (lane < 16u)
        v = __hip_atomic_load(&flags[lane], __ATOMIC_RELAXED,
                              __HIP_MEMORY_SCOPE_AGENT);
      if (__all((int)(v >= target))) break;
      __builtin_amdgcn_s_sleep(1);
    }
    __builtin_amdgcn_fence(__ATOMIC_ACQUIRE, "agent"); // invalidate stale L1/L2
  }
  __syncthreads();
}

// ------------------------------ recurrent kernel ---------------------------
// grid = 128: r = blockIdx>>4 (row-block of 32 rows), c = blockIdx&15 (h-cols
// [32c,32c+32)). LDS overlay region R (12288 B): phases 1-2 use stg(2KB)+
// zgSf(4KB, fp32); phase 3 uses muS(4KB bf16)+rawS(8KB fp32). Disjoint in time.
#define LDS_REC 159744
__global__ void __launch_bounds__(256, 1) rec_kernel(
    const bf16* __restrict__ Whs_g, const bf16* __restrict__ Wxz_g,
    const bf16* __restrict__ Wdf_g, const bf16* __restrict__ xgx,
    const float* __restrict__ noise, const float* __restrict__ b_d,
    float* __restrict__ out, bf16* __restrict__ hbuf, bf16* __restrict__ ubuf,
    bf16* __restrict__ zbuf, unsigned* __restrict__ bar,
    unsigned t0, unsigned tlen)
{
  extern __shared__ char smem[];
  bf16*  WhS  = (bf16*)(smem);            // 49152 el = 98304 B
  bf16*  WxzS = (bf16*)(smem + 98304);    // 6144 el = 12288 B
  bf16*  hA   = (bf16*)(smem + 110592);   // 16384 el  [kc16][q4][row32][j8]
  bf16*  zA   = (bf16*)(smem + 143360);   // 2048 el   [kc2][q4][row32][j8]
  bf16*  stg  = (bf16*)(smem + 147456);   // 1024 el   [q4][row32][j8]
  float* zgSf = (float*)(smem + 149504);  // 1024 el   [row32][col32] fp32
  bf16*  muS  = (bf16*)(smem + 147456);   // 2048 el   [row32][col64] (overlay)
  float* rawS = (float*)(smem + 151552);  // 2048 el   [row32][col64] fp32

  const unsigned tid = threadIdx.x;
  const unsigned wave = tid>>6, lane = tid&63u, q = lane>>4, m = lane&15u;
  const unsigned mt = wave&1u, gt = wave>>1;   // ph1: gate gt; ph2: N-tile gt
  const unsigned r = blockIdx.x>>4, c = blockIdx.x&15u;
  const unsigned b0 = (r&1u)*32u;
  const unsigned rowG0 = r*32u;
  const unsigned zrow = tid>>3, zi = tid&7u;
  unsigned* flags = bar + (size_t)r*64u;   // this row-block's 256-B flag line

  // ---- stage resident weights ----
  { const u32x4* s = (const u32x4*)(Whs_g + (size_t)c*49152u); u32x4* d = (u32x4*)WhS;
    #pragma unroll
    for (int i=0;i<24;i++) d[tid+256u*i] = s[tid+256u*i]; }
  { const u32x4* s = (const u32x4*)(Wxz_g + (size_t)c*6144u); u32x4* d = (u32x4*)WxzS;
    #pragma unroll
    for (int i=0;i<3;i++) d[tid+256u*i] = s[tid+256u*i]; }
  // ---- W_d fragments in VGPRs (cols [32*wave, 32*wave+32)) ----
  bf16x8 wd[16][2];
  #pragma unroll
  for (int kc=0;kc<16;kc++) {
    #pragma unroll
    for (int nw=0;nw<2;nw++)
      wd[kc][nw] = *(const bf16x8*)(Wdf_g +
          ((((unsigned)kc*4u+q)*128u + wave*32u + (unsigned)nw*16u + m)*8u));
  }
  float bd0 = b_d[wave*32u + m], bd1 = b_d[wave*32u + 16u + m];
  // ---- init state ----
  float hstate[4];   // fp32 carry of own h tile: rows 16mt+4q+reg, col gt*16+m
  if (t0 == 0) {
    u32x4 zz = {0,0,0,0};
    u32x4* d = (u32x4*)hA;
    #pragma unroll
    for (int i=0;i<8;i++) d[tid+256u*i] = zz;
    ((u32x4*)zA)[tid] = zz;
    #pragma unroll
    for (int reg=0;reg<4;reg++) hstate[reg] = 0.f;
    __syncthreads();
  } else {
    const u32x4* s = (const u32x4*)(hbuf + ((size_t)(1u*8u + r)*16u)*1024u); // parity 1
    u32x4* d = (u32x4*)hA;
    #pragma unroll
    for (int i=0;i<8;i++) d[tid+256u*i] = s[tid+256u*i];
    bf16x8 zv = *(const bf16x8*)(zbuf + ((size_t)(rowG0 + zrow)*64u + zi*8u));
    *(bf16x8*)(zA + ((size_t)zi*32u + zrow)*8u) = zv;
    __syncthreads();
    unsigned cl = gt*16u + m;
    #pragma unroll
    for (int reg=0;reg<4;reg++)
      hstate[reg] = (float)hA[((c*4u + (cl>>3))*32u + 16u*mt + 4u*q + (unsigned)reg)*8u + (cl&7u)];
  }

  const unsigned tend = t0 + tlen;
  for (unsigned t = t0; t < tend; ++t) {
    unsigned par = t & 1u;
    unsigned kb = 2u*(t - t0);
    // ---- early global loads (latency hidden under GEMMs) ----
    __bf16 xv1[2][4]; __bf16 xv2[4];
    { size_t base = ((size_t)((t - t0)*16u + c)*64u + b0 + 16u*mt + 4u*q)*96u + m;
      #pragma unroll
      for (int nt=0;nt<2;nt++)
        #pragma unroll
        for (int reg=0;reg<4;reg++)
          xv1[nt][reg] = xgx[base + (unsigned)reg*96u + gt*32u + (unsigned)nt*16u];
      #pragma unroll
      for (int reg=0;reg<4;reg++)
        xv2[reg] = xgx[base + (unsigned)reg*96u + 64u + gt*16u];
    }
    f32x4 eps0, eps1;
    { const float* np = noise + ((size_t)t*256u + rowG0 + zrow)*64u + zi*8u;
      eps0 = *(const f32x4*)np; eps1 = *(const f32x4*)(np + 4); }

    // ================= phase 1: z/r gates, u = r*h =================
    f32x4 accP0 = {0.f,0.f,0.f,0.f}, accP1 = {0.f,0.f,0.f,0.f};
    #pragma unroll
    for (int kc=0;kc<2;kc++) {
      bf16x8 a = *(const bf16x8*)(zA + (((unsigned)kc*4u+q)*32u + 16u*mt + m)*8u);
      accP0 = mfma16(a, *(const bf16x8*)(WxzS + (((unsigned)kc*4u+q)*96u + gt*32u + m)*8u), accP0);
      accP1 = mfma16(a, *(const bf16x8*)(WxzS + (((unsigned)kc*4u+q)*96u + gt*32u + 16u + m)*8u), accP1);
    }
    #pragma unroll
    for (int kc=0;kc<16;kc++) {
      bf16x8 a = *(const bf16x8*)(hA + (((unsigned)kc*4u+q)*32u + 16u*mt + m)*8u);
      accP0 = mfma16(a, *(const bf16x8*)(WhS + (((unsigned)kc*4u+q)*96u + gt*32u + m)*8u), accP0);
      accP1 = mfma16(a, *(const bf16x8*)(WhS + (((unsigned)kc*4u+q)*96u + gt*32u + 16u + m)*8u), accP1);
    }
    #pragma unroll
    for (int reg=0;reg<4;reg++) {
      unsigned rloc = 16u*mt + 4u*q + (unsigned)reg;
      float g0 = accP0[reg] + (float)xv1[0][reg];
      float g1 = accP1[reg] + (float)xv1[1][reg];
      float s0 = 1.f/(1.f + __expf(-g0));
      float s1 = 1.f/(1.f + __expf(-g1));
      if (gt == 0) {          // z-gate -> zgSf (fp32)
        zgSf[rloc*32u + m]       = s0;
        zgSf[rloc*32u + 16u + m] = s1;
      } else {                // r-gate -> u = r*h staged frag-major
        unsigned cl0 = m, cl1 = 16u + m;
        float h0 = (float)hA[((c*4u + (cl0>>3))*32u + rloc)*8u + (cl0&7u)];
        float h1 = (float)hA[((c*4u + (cl1>>3))*32u + rloc)*8u + (cl1&7u)];
        stg[((cl0>>3)*32u + rloc)*8u + (cl0&7u)] = (bf16)(s0*h0);
        stg[((cl1>>3)*32u + rloc)*8u + (cl1&7u)] = (bf16)(s1*h1);
      }
    }
    __syncthreads();
    // u slice -> ubuf (device-scope stores: visible at LLC)
    { size_t blk = ((size_t)(par*8u + r)*16u + c)*1024u;
      unsigned long long v = *(const unsigned long long*)(stg + (size_t)tid*4u);
      __hip_atomic_store((unsigned long long*)(ubuf + blk + (size_t)tid*4u), v,
                         __ATOMIC_RELAXED, __HIP_MEMORY_SCOPE_AGENT); }
    rb_barrier(flags, tid, lane, wave, c, kb + 1u);
    // load full u for own rows
    { const u32x4* s = (const u32x4*)(ubuf + ((size_t)(par*8u + r)*16u)*1024u);
      u32x4* d = (u32x4*)hA;
      #pragma unroll
      for (int i=0;i<8;i++) d[tid+256u*i] = s[tid+256u*i]; }
    __syncthreads();

    // ================= phase 2: n_cand, h_new =================
    // n preact = xg_n(x part, xv2) + z_prev@W_x[D:,2H:] + (r*h)@W_h[:,2H:]
    f32x4 accN = {0.f,0.f,0.f,0.f};
    #pragma unroll
    for (int kc=0;kc<2;kc++) {   // z_prev contribution to n-gate
      bf16x8 a = *(const bf16x8*)(zA + (((unsigned)kc*4u+q)*32u + 16u*mt + m)*8u);
      accN = mfma16(a, *(const bf16x8*)(WxzS + (((unsigned)kc*4u+q)*96u + 64u + gt*16u + m)*8u), accN);
    }
    #pragma unroll
    for (int kc=0;kc<16;kc++) {
      bf16x8 a = *(const bf16x8*)(hA + (((unsigned)kc*4u+q)*32u + 16u*mt + m)*8u);
      accN = mfma16(a, *(const bf16x8*)(WhS + (((unsigned)kc*4u+q)*96u + 64u + gt*16u + m)*8u), accN);
    }
    { unsigned colL2 = gt*16u + m;
      #pragma unroll
      for (int reg=0;reg<4;reg++) {
        unsigned rloc = 16u*mt + 4u*q + (unsigned)reg;
        float zg = zgSf[rloc*32u + colL2];
        float pre = accN[reg] + (float)xv2[reg];
        float e2 = __expf(2.f*pre);
        float nc = 1.f - 2.f/(e2 + 1.f);
        float hn = (1.f - zg)*nc + zg*hstate[reg];   // fp32 state carry
        hstate[reg] = hn;
        stg[((colL2>>3)*32u + rloc)*8u + (colL2&7u)] = (bf16)hn;
      }
    }
    __syncthreads();
    { size_t blk = ((size_t)(par*8u + r)*16u + c)*1024u;
      unsigned long long v = *(const unsigned long long*)(stg + (size_t)tid*4u);
      __hip_atomic_store((unsigned long long*)(hbuf + blk + (size_t)tid*4u), v,
                         __ATOMIC_RELAXED, __HIP_MEMORY_SCOPE_AGENT); }
    rb_barrier(flags, tid, lane, wave, c, kb + 2u);
    // load full h_new for own rows
    { const u32x4* s = (const u32x4*)(hbuf + ((size_t)(par*8u + r)*16u)*1024u);
      u32x4* d = (u32x4*)hA;
      #pragma unroll
      for (int i=0;i<8;i++) d[tid+256u*i] = s[tid+256u*i]; }
    __syncthreads();

    // ================= phase 3: dp = h_new@W_d, sample, outputs =========
    f32x4 dp00={0.f,0.f,0.f,0.f}, dp01={0.f,0.f,0.f,0.f};
    f32x4 dp10={0.f,0.f,0.f,0.f}, dp11={0.f,0.f,0.f,0.f};
    #pragma unroll
    for (int kc=0;kc<16;kc++) {
      bf16x8 a0 = *(const bf16x8*)(hA + (((unsigned)kc*4u+q)*32u + m)*8u);
      bf16x8 a1 = *(const bf16x8*)(hA + (((unsigned)kc*4u+q)*32u + 16u + m)*8u);
      dp00 = mfma16(a0, wd[kc][0], dp00);
      dp01 = mfma16(a0, wd[kc][1], dp01);
      dp10 = mfma16(a1, wd[kc][0], dp10);
      dp11 = mfma16(a1, wd[kc][1], dp11);
    }
    if (wave < 2u) {   // mu cols 0..63 -> muS (bf16)
      #pragma unroll
      for (int reg=0;reg<4;reg++) {
        unsigned r0 = 4u*q + (unsigned)reg;
        muS[r0*64u + wave*32u + m]              = (bf16)(dp00[reg] + bd0);
        muS[r0*64u + wave*32u + 16u + m]        = (bf16)(dp01[reg] + bd1);
        muS[(r0+16u)*64u + wave*32u + m]        = (bf16)(dp10[reg] + bd0);
        muS[(r0+16u)*64u + wave*32u + 16u + m]  = (bf16)(dp11[reg] + bd1);
      }
    } else {           // raw cols 64..127 -> rawS (fp32)
      unsigned cb = (wave - 2u)*32u;
      #pragma unroll
      for (int reg=0;reg<4;reg++) {
        unsigned r0 = 4u*q + (unsigned)reg;
        rawS[r0*64u + cb + m]              = dp00[reg] + bd0;
        rawS[r0*64u + cb + 16u + m]        = dp01[reg] + bd1;
        rawS[(r0+16u)*64u + cb + m]        = dp10[reg] + bd0;
        rawS[(r0+16u)*64u + cb + 16u + m]  = dp11[reg] + bd1;
      }
    }
    __syncthreads();
    {
      bf16x8 mu8 = *(const bf16x8*)(muS + (size_t)zrow*64u + zi*8u);
      f32x4 rw0 = *(const f32x4*)(rawS + (size_t)zrow*64u + zi*8u);
      f32x4 rw1 = *(const f32x4*)(rawS + (size_t)zrow*64u + zi*8u + 4u);
      float ent = 0.f, lp = 0.f;
      float zf[8];
      #pragma unroll
      for (int j=0;j<8;j++) {
        float raw = (j < 4) ? rw0[j] : rw1[j-4];
        float sp = (raw > 20.f) ? raw : __logf(1.f + __expf(raw));
        sp += 1e-4f;
        float ls = __logf(sp);
        float e = (j < 4) ? eps0[j] : eps1[j-4];
        float zv = (float)mu8[j] + sp*e;
        zf[j] = zv;
        ent += ls;
        lp  -= 0.5f*e*e + ls;
      }
      ent += 8.f*1.4189385332046727f;
      lp  -= 8.f*0.9189385332046727f;
      bf16x8 zb;
      #pragma unroll
      for (int j=0;j<8;j++) zb[j] = (bf16)zf[j];
      *(bf16x8*)(zA + ((size_t)zi*32u + zrow)*8u) = zb;
      if (c == 0) {
        float* zo = out + ((size_t)(rowG0 + zrow)*1024u + t)*64u + zi*8u;
        f32x4 o0 = {zf[0],zf[1],zf[2],zf[3]}, o1 = {zf[4],zf[5],zf[6],zf[7]};
        *(f32x4*)zo = o0; *((f32x4*)zo + 1) = o1;
        if (t == tend - 1u)  // carry z across chunk boundary
          *(bf16x8*)(zbuf + ((size_t)(rowG0 + zrow)*64u + zi*8u)) = zb;
      }
      ent += __shfl_down(ent, 4); lp += __shfl_down(lp, 4);
      ent += __shfl_down(ent, 2); lp += __shfl_down(lp, 2);
      ent += __shfl_down(ent, 1); lp += __shfl_down(lp, 1);
      if (zi == 0u && c == 0u) {
        out[16777216u + (size_t)(rowG0 + zrow)*1024u + t] = ent;
        out[17039360u + (size_t)(rowG0 + zrow)*1024u + t] = lp;
      }
    }
    __syncthreads();
  }
}

// ------------------------------- host --------------------------------------
extern "C" void kernel_launch(void* const* d_in, const int* in_sizes, int n_in,
                              void* d_out, int out_size, void* d_ws, size_t ws_size,
                              hipStream_t stream)
{
  const float* x     = (const float*)d_in[0];
  const float* noise = (const float*)d_in[1];
  const float* W_x   = (const float*)d_in[2];
  const float* W_h   = (const float*)d_in[3];
  const float* bias  = (const float*)d_in[4];
  const float* W_d   = (const float*)d_in[5];
  const float* b_d   = (const float*)d_in[6];
  float* out = (float*)d_out;
  char* ws = (char*)d_ws;

  size_t off = 0;
  unsigned* bar = (unsigned*)(ws + off);  off += 32768;   // 16ch x 8rb x 256B flag lines
  bf16* Wdf  = (bf16*)(ws + off);         off += 65536ull*2;
  bf16* Whs  = (bf16*)(ws + off);         off += 786432ull*2;
  bf16* Wxz  = (bf16*)(ws + off);         off += 98304ull*2;
  bf16* Wxx  = (bf16*)(ws + off);         off += 393216ull*2;
  bf16* hbuf = (bf16*)(ws + off);         off += 262144ull*2;
  bf16* ubuf = (bf16*)(ws + off);         off += 262144ull*2;
  bf16* zbuf = (bf16*)(ws + off);         off += 16384ull*2;
  bf16* xT   = (bf16*)(ws + off);         off += 16777216ull*2;
  bf16* xgx  = (bf16*)(ws + off);         // tlen*16*64*96 bf16 (chunked)
  size_t fixed = off;

  unsigned tlen = 1024;
  while (tlen > 64 && fixed + (size_t)tlen*196608ull > ws_size) tlen >>= 1;
  unsigned nch = 1024/tlen;

  hipMemsetAsync(bar, 0, 32768, stream);
  repack_kernel<<<5248, 256, 0, stream>>>(W_x, W_h, W_d, Whs, Wxz, Wdf, Wxx);
  xpose_kernel<<<1024, 256, 0, stream>>>(x, xT);
  hipFuncSetAttribute((const void*)rec_kernel,
                      hipFuncAttributeMaxDynamicSharedMemorySize, LDS_REC);
  for (unsigned ch = 0; ch < nch; ++ch) {
    unsigned t0 = ch*tlen;
    xgx_kernel<<<tlen*16, 256, 0, stream>>>(xT, Wxx, bias, xgx, t0);
    rec_kernel<<<NWG, 256, LDS_REC, stream>>>(Whs, Wxz, Wdf, xgx, noise, b_d,
                                              out, hbuf, ubuf, zbuf,
                                              bar + (size_t)ch*512u, t0, tlen);
  }
}

// Round 2
// 9235.703 us; speedup vs baseline: 1.6836x; 1.3850x over previous
//
#include <hip/hip_runtime.h>
#include <stdint.h>

// ---------------------------------------------------------------------------
// RnnInferenceNetwork: GRU-variant scan, T=1024, SB=256 rows, H=512, L=64.
// Design: 128 persistent wgs (8 row-blocks x 16 col-groups), weights resident
// in LDS (W_h/W_xz slices) + VGPRs (W_d frags), h/u state exchanged via LLC.
// x@W_x precomputed (bf16 MFMA).
// R3: per-row-block 16-WG flag barriers (no central counter).
// R4: (1) NO acquire fence anywhere in the loop -- all cross-WG state moves
//     via cache-bypassing agent-scope relaxed atomics on BOTH sides, so
//     L1/L2 keep xgx/noise/weights cached across steps (was: fence nuked
//     caches 2x/step -> 5x HBM over-fetch);
//     (2) X1 gather eliminated: P2 loads u MFMA A-fragments DIRECTLY from
//     LLC (ubuf slice layout == fragment layout, 16B per lane per slice);
//     (3) phase-3 output stores distributed across all 16 col-WGs (2 rows
//     each) to remove the c==0 straggler skew at every X1 barrier;
//     (4) P2 accumulator split into two interleaved MFMA chains.
// ---------------------------------------------------------------------------

#define NWG  128u

typedef __bf16 bf16;
typedef __attribute__((ext_vector_type(8))) __bf16 bf16x8;
typedef __attribute__((ext_vector_type(8))) short  s16x8;
typedef __attribute__((ext_vector_type(4))) float  f32x4;
typedef __attribute__((ext_vector_type(4))) unsigned int u32x4;
typedef __attribute__((ext_vector_type(2))) unsigned long long u64x2;

__device__ __forceinline__ f32x4 mfma16(bf16x8 a, bf16x8 b, f32x4 c) {
  return __builtin_amdgcn_mfma_f32_16x16x32_bf16(
      __builtin_bit_cast(s16x8, a), __builtin_bit_cast(s16x8, b), c, 0, 0, 0);
}

// --------------------------- repack weights --------------------------------
// B-fragment layout: [kc][q][n][j] ; element = W[k = kc*32+q*8+j][col(n)]
// Whs: [c16][kc16][q4][n96][j8]   col = (n/32)*512 + 32c + (n%32)   (W_h)
// Wxz: [c16][kc2 ][q4][n96][j8]   same col, rows 256..319 of W_x
// Wdf: [kc16][q4][n128][j8]       col = n                            (W_d)
// Wxx: [c16][kc8 ][q4][n96][j8]   same col, rows 0..255 of W_x
__global__ void repack_kernel(const float* __restrict__ W_x,
                              const float* __restrict__ W_h,
                              const float* __restrict__ W_d,
                              bf16* __restrict__ Whs, bf16* __restrict__ Wxz,
                              bf16* __restrict__ Wdf, bf16* __restrict__ Wxx)
{
  unsigned e = blockIdx.x*256u + threadIdx.x;
  if (e < 786432u) {
    unsigned c = e/49152u, r0 = e%49152u;
    unsigned kc = r0/3072u, r1 = r0%3072u;
    unsigned q = r1/768u, r2 = r1%768u;
    unsigned n = r2/8u, j = r2%8u;
    unsigned k = kc*32u + q*8u + j;
    unsigned colg = (n>>5)*512u + c*32u + (n&31u);
    Whs[e] = (bf16)W_h[k*1536u + colg];
  } else if (e < 884736u) {
    unsigned e1 = e - 786432u;
    unsigned c = e1/6144u, r0 = e1%6144u;
    unsigned kc = r0/3072u, r1 = r0%3072u;
    unsigned q = r1/768u, r2 = r1%768u;
    unsigned n = r2/8u, j = r2%8u;
    unsigned k = 256u + kc*32u + q*8u + j;
    unsigned colg = (n>>5)*512u + c*32u + (n&31u);
    Wxz[e1] = (bf16)W_x[k*1536u + colg];
  } else if (e < 950272u) {
    unsigned e2 = e - 884736u;
    unsigned kc = e2/4096u, r0 = e2%4096u;
    unsigned q = r0/1024u, r1 = r0%1024u;
    unsigned n = r1/8u, j = r1%8u;
    unsigned k = kc*32u + q*8u + j;
    Wdf[e2] = (bf16)W_d[k*128u + n];
  } else if (e < 1343488u) {
    unsigned e3 = e - 950272u;
    unsigned c = e3/24576u, r0 = e3%24576u;
    unsigned kc = r0/3072u, r1 = r0%3072u;
    unsigned q = r1/768u, r2 = r1%768u;
    unsigned n = r2/8u, j = r2%8u;
    unsigned k = kc*32u + q*8u + j;
    unsigned colg = (n>>5)*512u + c*32u + (n&31u);
    Wxx[e3] = (bf16)W_x[k*1536u + colg];
  }
}

// ----------------- transpose x [B][T][D] f32 -> xT [t][b][d] bf16 ----------
__global__ void xpose_kernel(const float* __restrict__ x, bf16* __restrict__ xT)
{
  unsigned t = blockIdx.x, tid = threadIdx.x;
  unsigned row = tid>>2, seg = tid&3u;
  const float* src = x + ((size_t)row*1024u + t)*256u + seg*64u;
  bf16* dst = xT + (size_t)t*16384u + row*256u + seg*64u;
  #pragma unroll
  for (int i = 0; i < 8; ++i) {
    f32x4 v0 = *(const f32x4*)(src + i*8);
    f32x4 v1 = *(const f32x4*)(src + i*8 + 4);
    bf16x8 o;
    #pragma unroll
    for (int j = 0; j < 4; ++j) { o[j] = (bf16)v0[j]; o[4+j] = (bf16)v1[j]; }
    *(bf16x8*)(dst + i*8) = o;
  }
}

// --------- xg_x precompute: xgx[lt][c][b64][n96] = x@W_x[:256]+b (bf16) ----
__global__ void __launch_bounds__(256) xgx_kernel(const bf16* __restrict__ xT,
                                                  const bf16* __restrict__ Wxx,
                                                  const float* __restrict__ bias,
                                                  bf16* __restrict__ xgx,
                                                  unsigned t0)
{
  __shared__ bf16 WxS[24576];
  __shared__ bf16 otile[6144];
  unsigned bid = blockIdx.x, lt = bid>>4, c = bid&15u, tid = threadIdx.x;
  unsigned t = t0 + lt;
  { const u32x4* s = (const u32x4*)(Wxx + (size_t)c*24576u); u32x4* d = (u32x4*)WxS;
    #pragma unroll
    for (int i=0;i<12;i++) d[tid+256u*i] = s[tid+256u*i]; }
  __syncthreads();
  unsigned wave = tid>>6, lane = tid&63u, q = lane>>4, m = lane&15u;
  f32x4 zero4 = {0.f,0.f,0.f,0.f};
  f32x4 acc[6];
  #pragma unroll
  for (int nt=0;nt<6;nt++) acc[nt] = zero4;
  const bf16* ap = xT + (size_t)t*16384u + (16u*wave + m)*256u + q*8u;
  #pragma unroll
  for (int kc=0;kc<8;kc++) {
    bf16x8 a = *(const bf16x8*)(ap + kc*32);
    #pragma unroll
    for (int nt=0;nt<6;nt++) {
      bf16x8 bb = *(const bf16x8*)(WxS + (((unsigned)kc*4u+q)*96u + (unsigned)nt*16u + m)*8u);
      acc[nt] = mfma16(a, bb, acc[nt]);
    }
  }
  #pragma unroll
  for (int nt=0;nt<6;nt++) {
    unsigned n = (unsigned)nt*16u + m;
    unsigned colg = (n>>5)*512u + c*32u + (n&31u);
    float bv = bias[colg];
    #pragma unroll
    for (int reg=0;reg<4;reg++)
      otile[(16u*wave + 4u*q + (unsigned)reg)*96u + n] = (bf16)(acc[nt][reg] + bv);
  }
  __syncthreads();
  { u32x4* d = (u32x4*)(xgx + (size_t)(lt*16u + c)*6144u);
    const u32x4* s = (const u32x4*)otile;
    #pragma unroll
    for (int i=0;i<3;i++) d[tid+256u*i] = s[tid+256u*i]; }
}

// ------------------- per-row-block barrier (16 WGs) ------------------------
// No acquire fence: every cross-WG byte is written AND read with agent-scope
// relaxed atomics (cache-bypassing, coherent at LLC), so no L1/L2 invalidate
// is needed -- read-only streams (xgx/noise) stay cached across steps.
// Ordering: __syncthreads drains vmcnt(0) in every wave, so all this-WG data
// stores are LLC-visible before tid 0 publishes the flag.
__device__ __forceinline__ void rb_barrier(unsigned* __restrict__ flags,
                                           unsigned tid, unsigned lane,
                                           unsigned wave, unsigned c,
                                           unsigned target)
{
  __syncthreads();   // drains vmcnt -> all wg data stores visible at LLC
  if (tid == 0)
    __hip_atomic_store(&flags[c], target, __ATOMIC_RELAXED,
                       __HIP_MEMORY_SCOPE_AGENT);
  if (wave == 0) {
    for (;;) {
      unsigned v = target;
      if (lane < 16u)
        v = __hip_atomic_load(&flags[lane], __ATOMIC_RELAXED,
                              __HIP_MEMORY_SCOPE_AGENT);
      if (__all((int)(v >= target))) break;
      __builtin_amdgcn_s_sleep(1);
    }
  }
  __syncthreads();
}

// ------------------------------ recurrent kernel ---------------------------
// grid = 128: r = blockIdx>>4 (row-block of 32 rows), c = blockIdx&15 (h-cols
// [32c,32c+32)). LDS overlay region (12288 B): phases 1-2 use stg(2KB)+
// zgSf(4KB, fp32); phase 3 uses muS(4KB bf16)+rawS(8KB fp32). Disjoint in time.
#define LDS_REC 159744
__global__ void __launch_bounds__(256, 1) rec_kernel(
    const bf16* __restrict__ Whs_g, const bf16* __restrict__ Wxz_g,
    const bf16* __restrict__ Wdf_g, const bf16* __restrict__ xgx,
    const float* __restrict__ noise, const float* __restrict__ b_d,
    float* __restrict__ out, bf16* __restrict__ hbuf, bf16* __restrict__ ubuf,
    bf16* __restrict__ zbuf, unsigned* __restrict__ bar,
    unsigned t0, unsigned tlen)
{
  extern __shared__ char smem[];
  bf16*  WhS  = (bf16*)(smem);            // 49152 el = 98304 B
  bf16*  WxzS = (bf16*)(smem + 98304);    // 6144 el = 12288 B
  bf16*  hA   = (bf16*)(smem + 110592);   // 16384 el  [kc16][q4][row32][j8]
  bf16*  zA   = (bf16*)(smem + 143360);   // 2048 el   [kc2][q4][row32][j8]
  bf16*  stg  = (bf16*)(smem + 147456);   // 1024 el   [q4][row32][j8]
  float* zgSf = (float*)(smem + 149504);  // 1024 el   [row32][col32] fp32
  bf16*  muS  = (bf16*)(smem + 147456);   // 2048 el   [row32][col64] (overlay)
  float* rawS = (float*)(smem + 151552);  // 2048 el   [row32][col64] fp32

  const unsigned tid = threadIdx.x;
  const unsigned wave = tid>>6, lane = tid&63u, q = lane>>4, m = lane&15u;
  const unsigned mt = wave&1u, gt = wave>>1;   // ph1: gate gt; ph2: N-tile gt
  const unsigned r = blockIdx.x>>4, c = blockIdx.x&15u;
  const unsigned b0 = (r&1u)*32u;
  const unsigned rowG0 = r*32u;
  const unsigned zrow = tid>>3, zi = tid&7u;
  unsigned* flags = bar + (size_t)r*64u;   // this row-block's 256-B flag line

  // ---- stage resident weights ----
  { const u32x4* s = (const u32x4*)(Whs_g + (size_t)c*49152u); u32x4* d = (u32x4*)WhS;
    #pragma unroll
    for (int i=0;i<24;i++) d[tid+256u*i] = s[tid+256u*i]; }
  { const u32x4* s = (const u32x4*)(Wxz_g + (size_t)c*6144u); u32x4* d = (u32x4*)WxzS;
    #pragma unroll
    for (int i=0;i<3;i++) d[tid+256u*i] = s[tid+256u*i]; }
  // ---- W_d fragments in VGPRs (cols [32*wave, 32*wave+32)) ----
  bf16x8 wd[16][2];
  #pragma unroll
  for (int kc=0;kc<16;kc++) {
    #pragma unroll
    for (int nw=0;nw<2;nw++)
      wd[kc][nw] = *(const bf16x8*)(Wdf_g +
          ((((unsigned)kc*4u+q)*128u + wave*32u + (unsigned)nw*16u + m)*8u));
  }
  float bd0 = b_d[wave*32u + m], bd1 = b_d[wave*32u + 16u + m];
  // ---- init state ----
  float hstate[4];   // fp32 carry of own h tile: rows 16mt+4q+reg, col gt*16+m
  if (t0 == 0) {
    u32x4 zz = {0,0,0,0};
    u32x4* d = (u32x4*)hA;
    #pragma unroll
    for (int i=0;i<8;i++) d[tid+256u*i] = zz;
    ((u32x4*)zA)[tid] = zz;
    #pragma unroll
    for (int reg=0;reg<4;reg++) hstate[reg] = 0.f;
    __syncthreads();
  } else {
    // plain loads OK: written by the PREVIOUS dispatch (kernel-boundary
    // release/acquire gives visibility + fresh caches)
    const u32x4* s = (const u32x4*)(hbuf + ((size_t)(1u*8u + r)*16u)*1024u); // parity 1
    u32x4* d = (u32x4*)hA;
    #pragma unroll
    for (int i=0;i<8;i++) d[tid+256u*i] = s[tid+256u*i];
    bf16x8 zv = *(const bf16x8*)(zbuf + ((size_t)(rowG0 + zrow)*64u + zi*8u));
    *(bf16x8*)(zA + ((size_t)zi*32u + zrow)*8u) = zv;
    __syncthreads();
    unsigned cl = gt*16u + m;
    #pragma unroll
    for (int reg=0;reg<4;reg++)
      hstate[reg] = (float)hA[((c*4u + (cl>>3))*32u + 16u*mt + 4u*q + (unsigned)reg)*8u + (cl&7u)];
  }

  const unsigned tend = t0 + tlen;
  for (unsigned t = t0; t < tend; ++t) {
    unsigned par = t & 1u;
    unsigned kb = 2u*(t - t0);
    // ---- early global loads (latency hidden under GEMMs; stay cached) ----
    __bf16 xv1[2][4]; __bf16 xv2[4];
    { size_t base = ((size_t)((t - t0)*16u + c)*64u + b0 + 16u*mt + 4u*q)*96u + m;
      #pragma unroll
      for (int nt=0;nt<2;nt++)
        #pragma unroll
        for (int reg=0;reg<4;reg++)
          xv1[nt][reg] = xgx[base + (unsigned)reg*96u + gt*32u + (unsigned)nt*16u];
      #pragma unroll
      for (int reg=0;reg<4;reg++)
        xv2[reg] = xgx[base + (unsigned)reg*96u + 64u + gt*16u];
    }
    f32x4 eps0, eps1;
    { const float* np = noise + ((size_t)t*256u + rowG0 + zrow)*64u + zi*8u;
      eps0 = *(const f32x4*)np; eps1 = *(const f32x4*)(np + 4); }

    // ================= phase 1: z/r gates, u = r*h =================
    // hA holds h(t-1): gathered at X2 of step t-1 (or init).
    f32x4 accP0 = {0.f,0.f,0.f,0.f}, accP1 = {0.f,0.f,0.f,0.f};
    #pragma unroll
    for (int kc=0;kc<2;kc++) {
      bf16x8 a = *(const bf16x8*)(zA + (((unsigned)kc*4u+q)*32u + 16u*mt + m)*8u);
      accP0 = mfma16(a, *(const bf16x8*)(WxzS + (((unsigned)kc*4u+q)*96u + gt*32u + m)*8u), accP0);
      accP1 = mfma16(a, *(const bf16x8*)(WxzS + (((unsigned)kc*4u+q)*96u + gt*32u + 16u + m)*8u), accP1);
    }
    #pragma unroll
    for (int kc=0;kc<16;kc++) {
      bf16x8 a = *(const bf16x8*)(hA + (((unsigned)kc*4u+q)*32u + 16u*mt + m)*8u);
      accP0 = mfma16(a, *(const bf16x8*)(WhS + (((unsigned)kc*4u+q)*96u + gt*32u + m)*8u), accP0);
      accP1 = mfma16(a, *(const bf16x8*)(WhS + (((unsigned)kc*4u+q)*96u + gt*32u + 16u + m)*8u), accP1);
    }
    #pragma unroll
    for (int reg=0;reg<4;reg++) {
      unsigned rloc = 16u*mt + 4u*q + (unsigned)reg;
      float g0 = accP0[reg] + (float)xv1[0][reg];
      float g1 = accP1[reg] + (float)xv1[1][reg];
      float s0 = 1.f/(1.f + __expf(-g0));
      float s1 = 1.f/(1.f + __expf(-g1));
      if (gt == 0) {          // z-gate -> zgSf (fp32)
        zgSf[rloc*32u + m]       = s0;
        zgSf[rloc*32u + 16u + m] = s1;
      } else {                // r-gate -> u = r*h staged frag-major
        unsigned cl0 = m, cl1 = 16u + m;
        float h0 = (float)hA[((c*4u + (cl0>>3))*32u + rloc)*8u + (cl0&7u)];
        float h1 = (float)hA[((c*4u + (cl1>>3))*32u + rloc)*8u + (cl1&7u)];
        stg[((cl0>>3)*32u + rloc)*8u + (cl0&7u)] = (bf16)(s0*h0);
        stg[((cl1>>3)*32u + rloc)*8u + (cl1&7u)] = (bf16)(s1*h1);
      }
    }
    __syncthreads();
    // u slice -> ubuf (agent-scope stores: visible at LLC)
    { size_t blk = ((size_t)(par*8u + r)*16u + c)*1024u;
      unsigned long long v = *(const unsigned long long*)(stg + (size_t)tid*4u);
      __hip_atomic_store((unsigned long long*)(ubuf + blk + (size_t)tid*4u), v,
                         __ATOMIC_RELAXED, __HIP_MEMORY_SCOPE_AGENT); }
    rb_barrier(flags, tid, lane, wave, c, kb + 1u);

    // ================= phase 2: n_cand, h_new =================
    // u MFMA A-fragments loaded DIRECTLY from LLC (no gather): ubuf slice
    // layout [q4][row32][j8] == fragment layout; lane (q,m), row-half mt
    // reads 16B (two 8B cache-bypassing atomics) per slice kc.
    unsigned long long uf0[16], uf1[16];
    { unsigned long long* ub = (unsigned long long*)ubuf;
      size_t b64 = ((size_t)(par*8u + r)*16u)*256u + (q*32u + 16u*mt + m)*2u;
      #pragma unroll
      for (int kc=0;kc<16;kc++) {
        uf0[kc] = __hip_atomic_load(ub + b64 + (unsigned)kc*256u,
                                    __ATOMIC_RELAXED, __HIP_MEMORY_SCOPE_AGENT);
        uf1[kc] = __hip_atomic_load(ub + b64 + (unsigned)kc*256u + 1u,
                                    __ATOMIC_RELAXED, __HIP_MEMORY_SCOPE_AGENT);
      }
    }
    // n preact = xg_n(x part, xv2) + z_prev@W_x[D:,2H:] + (r*h)@W_h[:,2H:]
    f32x4 accNa = {0.f,0.f,0.f,0.f}, accNb = {0.f,0.f,0.f,0.f};
    #pragma unroll
    for (int kc=0;kc<2;kc++) {   // z_prev contribution (zA in LDS, overlaps load latency)
      bf16x8 a = *(const bf16x8*)(zA + (((unsigned)kc*4u+q)*32u + 16u*mt + m)*8u);
      accNa = mfma16(a, *(const bf16x8*)(WxzS + (((unsigned)kc*4u+q)*96u + 64u + gt*16u + m)*8u), accNa);
    }
    #pragma unroll
    for (int kc=0;kc<16;kc++) {
      u64x2 tt; tt[0] = uf0[kc]; tt[1] = uf1[kc];
      bf16x8 a = __builtin_bit_cast(bf16x8, tt);
      f32x4& acc = (kc & 1) ? accNb : accNa;
      acc = mfma16(a, *(const bf16x8*)(WhS + (((unsigned)kc*4u+q)*96u + 64u + gt*16u + m)*8u), acc);
    }
    { unsigned colL2 = gt*16u + m;
      #pragma unroll
      for (int reg=0;reg<4;reg++) {
        unsigned rloc = 16u*mt + 4u*q + (unsigned)reg;
        float zg = zgSf[rloc*32u + colL2];
        float pre = accNa[reg] + accNb[reg] + (float)xv2[reg];
        float e2 = __expf(2.f*pre);
        float nc = 1.f - 2.f/(e2 + 1.f);
        float hn = (1.f - zg)*nc + zg*hstate[reg];   // fp32 state carry
        hstate[reg] = hn;
        stg[((colL2>>3)*32u + rloc)*8u + (colL2&7u)] = (bf16)hn;
      }
    }
    __syncthreads();
    { size_t blk = ((size_t)(par*8u + r)*16u + c)*1024u;
      unsigned long long v = *(const unsigned long long*)(stg + (size_t)tid*4u);
      __hip_atomic_store((unsigned long long*)(hbuf + blk + (size_t)tid*4u), v,
                         __ATOMIC_RELAXED, __HIP_MEMORY_SCOPE_AGENT); }
    rb_barrier(flags, tid, lane, wave, c, kb + 2u);
    // gather full h_new for own rows into hA (cache-bypassing loads; hA is
    // consumed by phase 3 AND next step's phase 1)
    { unsigned long long* s = (unsigned long long*)(hbuf + ((size_t)(par*8u + r)*16u)*1024u);
      unsigned long long* d = (unsigned long long*)hA;
      unsigned long long gtmp[16];
      #pragma unroll
      for (int i=0;i<16;i++)
        gtmp[i] = __hip_atomic_load(s + tid + 256u*i,
                                    __ATOMIC_RELAXED, __HIP_MEMORY_SCOPE_AGENT);
      #pragma unroll
      for (int i=0;i<16;i++) d[tid + 256u*i] = gtmp[i];
    }
    __syncthreads();

    // ================= phase 3: dp = h_new@W_d, sample, outputs =========
    f32x4 dp00={0.f,0.f,0.f,0.f}, dp01={0.f,0.f,0.f,0.f};
    f32x4 dp10={0.f,0.f,0.f,0.f}, dp11={0.f,0.f,0.f,0.f};
    #pragma unroll
    for (int kc=0;kc<16;kc++) {
      bf16x8 a0 = *(const bf16x8*)(hA + (((unsigned)kc*4u+q)*32u + m)*8u);
      bf16x8 a1 = *(const bf16x8*)(hA + (((unsigned)kc*4u+q)*32u + 16u + m)*8u);
      dp00 = mfma16(a0, wd[kc][0], dp00);
      dp01 = mfma16(a0, wd[kc][1], dp01);
      dp10 = mfma16(a1, wd[kc][0], dp10);
      dp11 = mfma16(a1, wd[kc][1], dp11);
    }
    if (wave < 2u) {   // mu cols 0..63 -> muS (bf16)
      #pragma unroll
      for (int reg=0;reg<4;reg++) {
        unsigned r0 = 4u*q + (unsigned)reg;
        muS[r0*64u + wave*32u + m]              = (bf16)(dp00[reg] + bd0);
        muS[r0*64u + wave*32u + 16u + m]        = (bf16)(dp01[reg] + bd1);
        muS[(r0+16u)*64u + wave*32u + m]        = (bf16)(dp10[reg] + bd0);
        muS[(r0+16u)*64u + wave*32u + 16u + m]  = (bf16)(dp11[reg] + bd1);
      }
    } else {           // raw cols 64..127 -> rawS (fp32)
      unsigned cb = (wave - 2u)*32u;
      #pragma unroll
      for (int reg=0;reg<4;reg++) {
        unsigned r0 = 4u*q + (unsigned)reg;
        rawS[r0*64u + cb + m]              = dp00[reg] + bd0;
        rawS[r0*64u + cb + 16u + m]        = dp01[reg] + bd1;
        rawS[(r0+16u)*64u + cb + m]        = dp10[reg] + bd0;
        rawS[(r0+16u)*64u + cb + 16u + m]  = dp11[reg] + bd1;
      }
    }
    __syncthreads();
    {
      bf16x8 mu8 = *(const bf16x8*)(muS + (size_t)zrow*64u + zi*8u);
      f32x4 rw0 = *(const f32x4*)(rawS + (size_t)zrow*64u + zi*8u);
      f32x4 rw1 = *(const f32x4*)(rawS + (size_t)zrow*64u + zi*8u + 4u);
      float ent = 0.f, lp = 0.f;
      float zf[8];
      #pragma unroll
      for (int j=0;j<8;j++) {
        float raw = (j < 4) ? rw0[j] : rw1[j-4];
        float sp = (raw > 20.f) ? raw : __logf(1.f + __expf(raw));
        sp += 1e-4f;
        float ls = __logf(sp);
        float e = (j < 4) ? eps0[j] : eps1[j-4];
        float zv = (float)mu8[j] + sp*e;
        zf[j] = zv;
        ent += ls;
        lp  -= 0.5f*e*e + ls;
      }
      ent += 8.f*1.4189385332046727f;
      lp  -= 8.f*0.9189385332046727f;
      bf16x8 zb;
      #pragma unroll
      for (int j=0;j<8;j++) zb[j] = (bf16)zf[j];
      *(bf16x8*)(zA + ((size_t)zi*32u + zrow)*8u) = zb;
      // R4: output stores distributed across the 16 col-WGs (2 rows each) to
      // remove the c==0 straggler skew at the next barrier.
      if ((zrow>>1) == c) {
        float* zo = out + ((size_t)(rowG0 + zrow)*1024u + t)*64u + zi*8u;
        f32x4 o0 = {zf[0],zf[1],zf[2],zf[3]}, o1 = {zf[4],zf[5],zf[6],zf[7]};
        *(f32x4*)zo = o0; *((f32x4*)zo + 1) = o1;
        if (t == tend - 1u)  // carry z across chunk boundary
          *(bf16x8*)(zbuf + ((size_t)(rowG0 + zrow)*64u + zi*8u)) = zb;
      }
      ent += __shfl_down(ent, 4); lp += __shfl_down(lp, 4);
      ent += __shfl_down(ent, 2); lp += __shfl_down(lp, 2);
      ent += __shfl_down(ent, 1); lp += __shfl_down(lp, 1);
      if (zi == 0u && (zrow>>1) == c) {
        out[16777216u + (size_t)(rowG0 + zrow)*1024u + t] = ent;
        out[17039360u + (size_t)(rowG0 + zrow)*1024u + t] = lp;
      }
    }
    __syncthreads();
  }
}

// ------------------------------- host --------------------------------------
extern "C" void kernel_launch(void* const* d_in, const int* in_sizes, int n_in,
                              void* d_out, int out_size, void* d_ws, size_t ws_size,
                              hipStream_t stream)
{
  const float* x     = (const float*)d_in[0];
  const float* noise = (const float*)d_in[1];
  const float* W_x   = (const float*)d_in[2];
  const float* W_h   = (const float*)d_in[3];
  const float* bias  = (const float*)d_in[4];
  const float* W_d   = (const float*)d_in[5];
  const float* b_d   = (const float*)d_in[6];
  float* out = (float*)d_out;
  char* ws = (char*)d_ws;

  size_t off = 0;
  unsigned* bar = (unsigned*)(ws + off);  off += 32768;   // 16ch x 8rb x 256B flag lines
  bf16* Wdf  = (bf16*)(ws + off);         off += 65536ull*2;
  bf16* Whs  = (bf16*)(ws + off);         off += 786432ull*2;
  bf16* Wxz  = (bf16*)(ws + off);         off += 98304ull*2;
  bf16* Wxx  = (bf16*)(ws + off);         off += 393216ull*2;
  bf16* hbuf = (bf16*)(ws + off);         off += 262144ull*2;
  bf16* ubuf = (bf16*)(ws + off);         off += 262144ull*2;
  bf16* zbuf = (bf16*)(ws + off);         off += 16384ull*2;
  bf16* xT   = (bf16*)(ws + off);         off += 16777216ull*2;
  bf16* xgx  = (bf16*)(ws + off);         // tlen*16*64*96 bf16 (chunked)
  size_t fixed = off;

  unsigned tlen = 1024;
  while (tlen > 64 && fixed + (size_t)tlen*196608ull > ws_size) tlen >>= 1;
  unsigned nch = 1024/tlen;

  hipMemsetAsync(bar, 0, 32768, stream);
  repack_kernel<<<5248, 256, 0, stream>>>(W_x, W_h, W_d, Whs, Wxz, Wdf, Wxx);
  xpose_kernel<<<1024, 256, 0, stream>>>(x, xT);
  hipFuncSetAttribute((const void*)rec_kernel,
                      hipFuncAttributeMaxDynamicSharedMemorySize, LDS_REC);
  for (unsigned ch = 0; ch < nch; ++ch) {
    unsigned t0 = ch*tlen;
    xgx_kernel<<<tlen*16, 256, 0, stream>>>(xT, Wxx, bias, xgx, t0);
    rec_kernel<<<NWG, 256, LDS_REC, stream>>>(Whs, Wxz, Wdf, xgx, noise, b_d,
                                              out, hbuf, ubuf, zbuf,
                                              bar + (size_t)ch*512u, t0, tlen);
  }
}

// Round 4
// 9010.541 us; speedup vs baseline: 1.7257x; 1.0250x over previous
//
#include <hip/hip_runtime.h>
#include <stdint.h>

// ---------------------------------------------------------------------------
// RnnInferenceNetwork: GRU-variant scan, T=1024, SB=256 rows, H=512, L=64.
// Design: 128 persistent wgs (8 row-blocks x 16 col-groups), weights resident
// in LDS (W_h/W_xz slices) + VGPRs (W_d frags). x@W_x precomputed (bf16 MFMA).
// R3: per-row-block 16-WG flag barriers. R4: fence-free LLC exchange via
// cache-bypassing agent atomics; direct LLC->MFMA u-fragments; distributed
// output stores.
// R5: XCD-local exchange (r=bid%8 -> one XCD per row-block under round-robin
// dispatch): plain write-through stores + sc0 loads through the shared L2.
// R6: HARDENED. The L2 fast path is enabled only after an on-device
// self-test proves, via the trusted LLC barrier: (a) all 16 WGs share an
// XCC_ID; (b) plain stores from one CU are sc0-visible on other CUs after a
// vmcnt drain; (c) sc0 re-reads of rewritten lines return FRESH data (no
// stale-L1 -> no poll deadlock). Any failure -> proven R4 LLC path.
// ---------------------------------------------------------------------------

#define NWG  128u

typedef __bf16 bf16;
typedef __attribute__((ext_vector_type(8))) __bf16 bf16x8;
typedef __attribute__((ext_vector_type(8))) short  s16x8;
typedef __attribute__((ext_vector_type(4))) float  f32x4;
typedef __attribute__((ext_vector_type(4))) unsigned int u32x4;
typedef __attribute__((ext_vector_type(2))) unsigned long long u64x2;

__device__ __forceinline__ f32x4 mfma16(bf16x8 a, bf16x8 b, f32x4 c) {
  return __builtin_amdgcn_mfma_f32_16x16x32_bf16(
      __builtin_bit_cast(s16x8, a), __builtin_bit_cast(s16x8, b), c, 0, 0, 0);
}

// ---- sc0 load helpers: bypass L1, serviced by the XCD-local L2 ------------
__device__ __forceinline__ unsigned ld_u32_sc0(const unsigned* p) {
  unsigned v;
  asm volatile("global_load_dword %0, %1, off sc0\n\ts_waitcnt vmcnt(0)"
               : "=v"(v) : "v"(p) : "memory");
  return v;
}
__device__ __forceinline__ u32x4 ld_u128_sc0(const void* p) {
  u32x4 v;
  asm volatile("global_load_dwordx4 %0, %1, off sc0" : "=v"(v) : "v"(p));
  return v;
}
__device__ __forceinline__ void vm_wait0() {
  asm volatile("s_waitcnt vmcnt(0)" ::: "memory");
  __builtin_amdgcn_sched_barrier(0);   // keep consumers after the wait
}

// --------------------------- repack weights --------------------------------
// B-fragment layout: [kc][q][n][j] ; element = W[k = kc*32+q*8+j][col(n)]
// Whs: [c16][kc16][q4][n96][j8]   col = (n/32)*512 + 32c + (n%32)   (W_h)
// Wxz: [c16][kc2 ][q4][n96][j8]   same col, rows 256..319 of W_x
// Wdf: [kc16][q4][n128][j8]       col = n                            (W_d)
// Wxx: [c16][kc8 ][q4][n96][j8]   same col, rows 0..255 of W_x
__global__ void repack_kernel(const float* __restrict__ W_x,
                              const float* __restrict__ W_h,
                              const float* __restrict__ W_d,
                              bf16* __restrict__ Whs, bf16* __restrict__ Wxz,
                              bf16* __restrict__ Wdf, bf16* __restrict__ Wxx)
{
  unsigned e = blockIdx.x*256u + threadIdx.x;
  if (e < 786432u) {
    unsigned c = e/49152u, r0 = e%49152u;
    unsigned kc = r0/3072u, r1 = r0%3072u;
    unsigned q = r1/768u, r2 = r1%768u;
    unsigned n = r2/8u, j = r2%8u;
    unsigned k = kc*32u + q*8u + j;
    unsigned colg = (n>>5)*512u + c*32u + (n&31u);
    Whs[e] = (bf16)W_h[k*1536u + colg];
  } else if (e < 884736u) {
    unsigned e1 = e - 786432u;
    unsigned c = e1/6144u, r0 = e1%6144u;
    unsigned kc = r0/3072u, r1 = r0%3072u;
    unsigned q = r1/768u, r2 = r1%768u;
    unsigned n = r2/8u, j = r2%8u;
    unsigned k = 256u + kc*32u + q*8u + j;
    unsigned colg = (n>>5)*512u + c*32u + (n&31u);
    Wxz[e1] = (bf16)W_x[k*1536u + colg];
  } else if (e < 950272u) {
    unsigned e2 = e - 884736u;
    unsigned kc = e2/4096u, r0 = e2%4096u;
    unsigned q = r0/1024u, r1 = r0%1024u;
    unsigned n = r1/8u, j = r1%8u;
    unsigned k = kc*32u + q*8u + j;
    Wdf[e2] = (bf16)W_d[k*128u + n];
  } else if (e < 1343488u) {
    unsigned e3 = e - 950272u;
    unsigned c = e3/24576u, r0 = e3%24576u;
    unsigned kc = r0/3072u, r1 = r0%3072u;
    unsigned q = r1/768u, r2 = r1%768u;
    unsigned n = r2/8u, j = r2%8u;
    unsigned k = kc*32u + q*8u + j;
    unsigned colg = (n>>5)*512u + c*32u + (n&31u);
    Wxx[e3] = (bf16)W_x[k*1536u + colg];
  }
}

// ----------------- transpose x [B][T][D] f32 -> xT [t][b][d] bf16 ----------
__global__ void xpose_kernel(const float* __restrict__ x, bf16* __restrict__ xT)
{
  unsigned t = blockIdx.x, tid = threadIdx.x;
  unsigned row = tid>>2, seg = tid&3u;
  const float* src = x + ((size_t)row*1024u + t)*256u + seg*64u;
  bf16* dst = xT + (size_t)t*16384u + row*256u + seg*64u;
  #pragma unroll
  for (int i = 0; i < 8; ++i) {
    f32x4 v0 = *(const f32x4*)(src + i*8);
    f32x4 v1 = *(const f32x4*)(src + i*8 + 4);
    bf16x8 o;
    #pragma unroll
    for (int j = 0; j < 4; ++j) { o[j] = (bf16)v0[j]; o[4+j] = (bf16)v1[j]; }
    *(bf16x8*)(dst + i*8) = o;
  }
}

// --------- xg_x precompute: xgx[lt][c][b64][n96] = x@W_x[:256]+b (bf16) ----
__global__ void __launch_bounds__(256) xgx_kernel(const bf16* __restrict__ xT,
                                                  const bf16* __restrict__ Wxx,
                                                  const float* __restrict__ bias,
                                                  bf16* __restrict__ xgx,
                                                  unsigned t0)
{
  __shared__ bf16 WxS[24576];
  __shared__ bf16 otile[6144];
  unsigned bid = blockIdx.x, lt = bid>>4, c = bid&15u, tid = threadIdx.x;
  unsigned t = t0 + lt;
  { const u32x4* s = (const u32x4*)(Wxx + (size_t)c*24576u); u32x4* d = (u32x4*)WxS;
    #pragma unroll
    for (int i=0;i<12;i++) d[tid+256u*i] = s[tid+256u*i]; }
  __syncthreads();
  unsigned wave = tid>>6, lane = tid&63u, q = lane>>4, m = lane&15u;
  f32x4 zero4 = {0.f,0.f,0.f,0.f};
  f32x4 acc[6];
  #pragma unroll
  for (int nt=0;nt<6;nt++) acc[nt] = zero4;
  const bf16* ap = xT + (size_t)t*16384u + (16u*wave + m)*256u + q*8u;
  #pragma unroll
  for (int kc=0;kc<8;kc++) {
    bf16x8 a = *(const bf16x8*)(ap + kc*32);
    #pragma unroll
    for (int nt=0;nt<6;nt++) {
      bf16x8 bb = *(const bf16x8*)(WxS + (((unsigned)kc*4u+q)*96u + (unsigned)nt*16u + m)*8u);
      acc[nt] = mfma16(a, bb, acc[nt]);
    }
  }
  #pragma unroll
  for (int nt=0;nt<6;nt++) {
    unsigned n = (unsigned)nt*16u + m;
    unsigned colg = (n>>5)*512u + c*32u + (n&31u);
    float bv = bias[colg];
    #pragma unroll
    for (int reg=0;reg<4;reg++)
      otile[(16u*wave + 4u*q + (unsigned)reg)*96u + n] = (bf16)(acc[nt][reg] + bv);
  }
  __syncthreads();
  { u32x4* d = (u32x4*)(xgx + (size_t)(lt*16u + c)*6144u);
    const u32x4* s = (const u32x4*)otile;
    #pragma unroll
    for (int i=0;i<3;i++) d[tid+256u*i] = s[tid+256u*i]; }
}

// ------------------- per-row-block barriers (16 WGs) -----------------------
// LLC variant (R4, proven): agent-scope cache-bypassing atomics; no fence
// needed because every cross-WG byte moves via agent atomics on both sides.
__device__ __forceinline__ void rb_bar_llc(unsigned* __restrict__ flags,
                                           unsigned tid, unsigned lane,
                                           unsigned wave, unsigned c,
                                           unsigned target)
{
  __syncthreads();   // drains vmcnt -> all wg data stores visible at LLC
  if (tid == 0)
    __hip_atomic_store(&flags[c], target, __ATOMIC_RELAXED,
                       __HIP_MEMORY_SCOPE_AGENT);
  if (wave == 0) {
    for (;;) {
      unsigned v = target;
      if (lane < 16u)
        v = __hip_atomic_load(&flags[lane], __ATOMIC_RELAXED,
                              __HIP_MEMORY_SCOPE_AGENT);
      if (__all((int)(v >= target))) break;
      __builtin_amdgcn_s_sleep(1);
    }
  }
  __syncthreads();
}
// L2 variant: all 16 WGs runtime-verified on one XCD with working sc0
// semantics. Plain write-through flag store (vmcnt retire = L2 ack); poll
// with sc0 loads (bypass L1, read local L2).
__device__ __forceinline__ void rb_bar_l2(unsigned* __restrict__ flags,
                                          unsigned tid, unsigned lane,
                                          unsigned wave, unsigned c,
                                          unsigned target)
{
  __syncthreads();   // drains vmcnt -> all wg data stores ack'd at L2
  if (tid == 0)
    __hip_atomic_store(&flags[c], target, __ATOMIC_RELAXED,
                       __HIP_MEMORY_SCOPE_WORKGROUP);   // plain store
  if (wave == 0) {
    for (;;) {
      unsigned v = target;
      if (lane < 16u) v = ld_u32_sc0(&flags[lane]);
      if (__all((int)(v >= target))) break;
    }
  }
  __syncthreads();
}

// ------------------------------ recurrent kernel ---------------------------
// grid = 128: r = blockIdx%8 (row-block of 32 rows; %8 -> one XCD under
// round-robin dispatch), c = blockIdx/8 (h-cols [32c,32c+32)). LDS overlay
// (12288 B): phases 1-2 use stg(2KB)+zgSf(4KB); phase 3 muS(4KB)+rawS(8KB).
// bar region per row-block: 512 u32 (2 KB):
//   [0..15] LLC flags | [32..47] xcd ids | [64..79] L2 flags |
//   [96..111] selftest verdicts | [128..383] selftest slots (256 u32)
#define LDS_REC 159744
__global__ void __launch_bounds__(256, 1) rec_kernel(
    const bf16* __restrict__ Whs_g, const bf16* __restrict__ Wxz_g,
    const bf16* __restrict__ Wdf_g, const bf16* __restrict__ xgx,
    const float* __restrict__ noise, const float* __restrict__ b_d,
    float* __restrict__ out, bf16* __restrict__ hbuf, bf16* __restrict__ ubuf,
    bf16* __restrict__ zbuf, unsigned* __restrict__ bar,
    unsigned t0, unsigned tlen)
{
  extern __shared__ char smem[];
  bf16*  WhS  = (bf16*)(smem);            // 49152 el = 98304 B
  bf16*  WxzS = (bf16*)(smem + 98304);    // 6144 el = 12288 B
  bf16*  hA   = (bf16*)(smem + 110592);   // 16384 el  [kc16][q4][row32][j8]
  bf16*  zA   = (bf16*)(smem + 143360);   // 2048 el   [kc2][q4][row32][j8]
  bf16*  stg  = (bf16*)(smem + 147456);   // 1024 el   [q4][row32][j8]
  float* zgSf = (float*)(smem + 149504);  // 1024 el   [row32][col32] fp32
  bf16*  muS  = (bf16*)(smem + 147456);   // 2048 el   [row32][col64] (overlay)
  float* rawS = (float*)(smem + 151552);  // 2048 el   [row32][col64] fp32

  const unsigned tid = threadIdx.x;
  const unsigned wave = tid>>6, lane = tid&63u, q = lane>>4, m = lane&15u;
  const unsigned mt = wave&1u, gt = wave>>1;   // ph1: gate gt; ph2: N-tile gt
  const unsigned r = blockIdx.x & 7u, c = blockIdx.x >> 3;   // R5 remap
  const unsigned b0 = (r&1u)*32u;
  const unsigned rowG0 = r*32u;
  const unsigned zrow = tid>>3, zi = tid&7u;
  unsigned* rb = bar + (size_t)r*512u;

  // ---- stage resident weights ----
  { const u32x4* s = (const u32x4*)(Whs_g + (size_t)c*49152u); u32x4* d = (u32x4*)WhS;
    #pragma unroll
    for (int i=0;i<24;i++) d[tid+256u*i] = s[tid+256u*i]; }
  { const u32x4* s = (const u32x4*)(Wxz_g + (size_t)c*6144u); u32x4* d = (u32x4*)WxzS;
    #pragma unroll
    for (int i=0;i<3;i++) d[tid+256u*i] = s[tid+256u*i]; }
  // ---- W_d fragments in VGPRs (cols [32*wave, 32*wave+32)) ----
  bf16x8 wd[16][2];
  #pragma unroll
  for (int kc=0;kc<16;kc++) {
    #pragma unroll
    for (int nw=0;nw<2;nw++)
      wd[kc][nw] = *(const bf16x8*)(Wdf_g +
          ((((unsigned)kc*4u+q)*128u + wave*32u + (unsigned)nw*16u + m)*8u));
  }
  float bd0 = b_d[wave*32u + m], bd1 = b_d[wave*32u + 16u + m];

  // =================== R6 self-testing XCD handshake =====================
  bool l2m;
  {
    unsigned* ts = rb + 128u;          // 256-word test slots
    unsigned myxcd;
    asm volatile("s_getreg_b32 %0, hwreg(HW_REG_XCC_ID)" : "=s"(myxcd));
    myxcd = (myxcd & 15u) + 1u;
    if (tid == 0)
      __hip_atomic_store(&rb[32u + c], myxcd, __ATOMIC_RELAXED,
                         __HIP_MEMORY_SCOPE_AGENT);
    rb_bar_llc(rb, tid, lane, wave, c, 1u);
    bool xcdok;
    { unsigned v = myxcd;
      if (lane < 16u)
        v = __hip_atomic_load(&rb[32u + lane], __ATOMIC_RELAXED,
                              __HIP_MEMORY_SCOPE_AGENT);
      xcdok = (bool)__all((int)(v == myxcd));
    }
    // pattern A: plain (workgroup-scope) stores, exactly like loop data path
    if (tid < 16u)
      __hip_atomic_store(&ts[c*16u + tid], 0xA0000000u + (c<<8) + tid,
                         __ATOMIC_RELAXED, __HIP_MEMORY_SCOPE_WORKGROUP);
    rb_bar_llc(rb, tid, lane, wave, c, 2u);
    unsigned jj = tid>>4, ii = tid&15u;
    bool okA = (ld_u32_sc0(&ts[tid]) == 0xA0000000u + (jj<<8) + ii);
    rb_bar_llc(rb, tid, lane, wave, c, 3u);   // reads done before overwrite
    // pattern B: rewrite the SAME lines; re-read from the SAME threads ->
    // detects stale-L1 on sc0 (the deadlock mode)
    if (tid < 16u)
      __hip_atomic_store(&ts[c*16u + tid], 0xB0000000u + (c<<8) + tid,
                         __ATOMIC_RELAXED, __HIP_MEMORY_SCOPE_WORKGROUP);
    rb_bar_llc(rb, tid, lane, wave, c, 4u);
    bool okB = (ld_u32_sc0(&ts[tid]) == 0xB0000000u + (jj<<8) + ii);
    // WG-wide AND via LDS scratch
    unsigned* sc = (unsigned*)stg;
    sc[0] = 1u; __syncthreads();
    if (!(okA && okB)) sc[0] = 0u;
    __syncthreads();
    unsigned myok = (sc[0] != 0u) ? 1u : 2u;
    __syncthreads();
    if (tid == 0)
      __hip_atomic_store(&rb[96u + c], myok, __ATOMIC_RELAXED,
                         __HIP_MEMORY_SCOPE_AGENT);
    rb_bar_llc(rb, tid, lane, wave, c, 5u);
    { unsigned v = 1u;
      if (lane < 16u)
        v = __hip_atomic_load(&rb[96u + lane], __ATOMIC_RELAXED,
                              __HIP_MEMORY_SCOPE_AGENT);
      l2m = xcdok && (bool)__all((int)(v == 1u));
    }
  }
  unsigned* l2f = rb + 64u;

  // ---- init state ----
  float hstate[4];   // fp32 carry of own h tile: rows 16mt+4q+reg, col gt*16+m
  if (t0 == 0) {
    u32x4 zz = {0,0,0,0};
    u32x4* d = (u32x4*)hA;
    #pragma unroll
    for (int i=0;i<8;i++) d[tid+256u*i] = zz;
    ((u32x4*)zA)[tid] = zz;
    #pragma unroll
    for (int reg=0;reg<4;reg++) hstate[reg] = 0.f;
    __syncthreads();
  } else {
    // written by the PREVIOUS dispatch (kernel-boundary flush gives visibility)
    const u32x4* s = (const u32x4*)(hbuf + ((size_t)(1u*8u + r)*16u)*1024u); // parity 1
    u32x4* d = (u32x4*)hA;
    #pragma unroll
    for (int i=0;i<8;i++) d[tid+256u*i] = s[tid+256u*i];
    bf16x8 zv = *(const bf16x8*)(zbuf + ((size_t)(rowG0 + zrow)*64u + zi*8u));
    *(bf16x8*)(zA + ((size_t)zi*32u + zrow)*8u) = zv;
    __syncthreads();
    unsigned cl = gt*16u + m;
    #pragma unroll
    for (int reg=0;reg<4;reg++)
      hstate[reg] = (float)hA[((c*4u + (cl>>3))*32u + 16u*mt + 4u*q + (unsigned)reg)*8u + (cl&7u)];
  }

  const unsigned tend = t0 + tlen;
  for (unsigned t = t0; t < tend; ++t) {
    unsigned par = t & 1u;
    unsigned kb = 2u*(t - t0);
    // ---- early global loads (latency hidden under GEMMs; stay cached) ----
    __bf16 xv1[2][4]; __bf16 xv2[4];
    { size_t base = ((size_t)((t - t0)*16u + c)*64u + b0 + 16u*mt + 4u*q)*96u + m;
      #pragma unroll
      for (int nt=0;nt<2;nt++)
        #pragma unroll
        for (int reg=0;reg<4;reg++)
          xv1[nt][reg] = xgx[base + (unsigned)reg*96u + gt*32u + (unsigned)nt*16u];
      #pragma unroll
      for (int reg=0;reg<4;reg++)
        xv2[reg] = xgx[base + (unsigned)reg*96u + 64u + gt*16u];
    }
    f32x4 eps0, eps1;
    { const float* np = noise + ((size_t)t*256u + rowG0 + zrow)*64u + zi*8u;
      eps0 = *(const f32x4*)np; eps1 = *(const f32x4*)(np + 4); }

    // ================= phase 1: z/r gates, u = r*h =================
    f32x4 accP0 = {0.f,0.f,0.f,0.f}, accP1 = {0.f,0.f,0.f,0.f};
    #pragma unroll
    for (int kc=0;kc<2;kc++) {
      bf16x8 a = *(const bf16x8*)(zA + (((unsigned)kc*4u+q)*32u + 16u*mt + m)*8u);
      accP0 = mfma16(a, *(const bf16x8*)(WxzS + (((unsigned)kc*4u+q)*96u + gt*32u + m)*8u), accP0);
      accP1 = mfma16(a, *(const bf16x8*)(WxzS + (((unsigned)kc*4u+q)*96u + gt*32u + 16u + m)*8u), accP1);
    }
    #pragma unroll
    for (int kc=0;kc<16;kc++) {
      bf16x8 a = *(const bf16x8*)(hA + (((unsigned)kc*4u+q)*32u + 16u*mt + m)*8u);
      accP0 = mfma16(a, *(const bf16x8*)(WhS + (((unsigned)kc*4u+q)*96u + gt*32u + m)*8u), accP0);
      accP1 = mfma16(a, *(const bf16x8*)(WhS + (((unsigned)kc*4u+q)*96u + gt*32u + 16u + m)*8u), accP1);
    }
    #pragma unroll
    for (int reg=0;reg<4;reg++) {
      unsigned rloc = 16u*mt + 4u*q + (unsigned)reg;
      float g0 = accP0[reg] + (float)xv1[0][reg];
      float g1 = accP1[reg] + (float)xv1[1][reg];
      float s0 = 1.f/(1.f + __expf(-g0));
      float s1 = 1.f/(1.f + __expf(-g1));
      if (gt == 0) {          // z-gate -> zgSf (fp32)
        zgSf[rloc*32u + m]       = s0;
        zgSf[rloc*32u + 16u + m] = s1;
      } else {                // r-gate -> u = r*h staged frag-major
        unsigned cl0 = m, cl1 = 16u + m;
        float h0 = (float)hA[((c*4u + (cl0>>3))*32u + rloc)*8u + (cl0&7u)];
        float h1 = (float)hA[((c*4u + (cl1>>3))*32u + rloc)*8u + (cl1&7u)];
        stg[((cl0>>3)*32u + rloc)*8u + (cl0&7u)] = (bf16)(s0*h0);
        stg[((cl1>>3)*32u + rloc)*8u + (cl1&7u)] = (bf16)(s1*h1);
      }
    }
    __syncthreads();
    // u slice -> ubuf
    { size_t blk = ((size_t)(par*8u + r)*16u + c)*1024u;
      unsigned long long v = *(const unsigned long long*)(stg + (size_t)tid*4u);
      if (l2m)
        __hip_atomic_store((unsigned long long*)(ubuf + blk + (size_t)tid*4u), v,
                           __ATOMIC_RELAXED, __HIP_MEMORY_SCOPE_WORKGROUP);
      else
        __hip_atomic_store((unsigned long long*)(ubuf + blk + (size_t)tid*4u), v,
                           __ATOMIC_RELAXED, __HIP_MEMORY_SCOPE_AGENT); }
    if (l2m) rb_bar_l2 (l2f, tid, lane, wave, c, kb + 1u);
    else     rb_bar_llc(rb,  tid, lane, wave, c, kb + 6u);

    // ================= phase 2: n_cand, h_new =================
    // u MFMA A-fragments loaded DIRECTLY (no gather): ubuf slice layout
    // [q4][row32][j8] == fragment layout; 16B per lane per c-slice.
    bf16x8 ufr[16];
    if (l2m) {
      const char* ub = (const char*)ubuf + (size_t)(par*8u + r)*32768u
                       + (q*32u + 16u*mt + m)*16u;
      u32x4 tmp[16];
      #pragma unroll
      for (int kc=0;kc<16;kc++) tmp[kc] = ld_u128_sc0(ub + kc*2048);
      vm_wait0();
      #pragma unroll
      for (int kc=0;kc<16;kc++) ufr[kc] = __builtin_bit_cast(bf16x8, tmp[kc]);
    } else {
      unsigned long long* ubp = (unsigned long long*)ubuf;
      size_t b64 = ((size_t)(par*8u + r)*16u)*256u + (q*32u + 16u*mt + m)*2u;
      #pragma unroll
      for (int kc=0;kc<16;kc++) {
        unsigned long long a0 = __hip_atomic_load(ubp + b64 + (unsigned)kc*256u,
                                    __ATOMIC_RELAXED, __HIP_MEMORY_SCOPE_AGENT);
        unsigned long long a1 = __hip_atomic_load(ubp + b64 + (unsigned)kc*256u + 1u,
                                    __ATOMIC_RELAXED, __HIP_MEMORY_SCOPE_AGENT);
        u64x2 tt; tt[0] = a0; tt[1] = a1;
        ufr[kc] = __builtin_bit_cast(bf16x8, tt);
      }
    }
    // n preact = xg_n(x part, xv2) + z_prev@W_x[D:,2H:] + (r*h)@W_h[:,2H:]
    f32x4 accNa = {0.f,0.f,0.f,0.f}, accNb = {0.f,0.f,0.f,0.f};
    #pragma unroll
    for (int kc=0;kc<2;kc++) {   // z_prev contribution (zA in LDS)
      bf16x8 a = *(const bf16x8*)(zA + (((unsigned)kc*4u+q)*32u + 16u*mt + m)*8u);
      accNa = mfma16(a, *(const bf16x8*)(WxzS + (((unsigned)kc*4u+q)*96u + 64u + gt*16u + m)*8u), accNa);
    }
    #pragma unroll
    for (int kc=0;kc<16;kc++) {
      f32x4& acc = (kc & 1) ? accNb : accNa;
      acc = mfma16(ufr[kc], *(const bf16x8*)(WhS + (((unsigned)kc*4u+q)*96u + 64u + gt*16u + m)*8u), acc);
    }
    { unsigned colL2 = gt*16u + m;
      #pragma unroll
      for (int reg=0;reg<4;reg++) {
        unsigned rloc = 16u*mt + 4u*q + (unsigned)reg;
        float zg = zgSf[rloc*32u + colL2];
        float pre = accNa[reg] + accNb[reg] + (float)xv2[reg];
        float e2 = __expf(2.f*pre);
        float nc = 1.f - 2.f/(e2 + 1.f);
        float hn = (1.f - zg)*nc + zg*hstate[reg];   // fp32 state carry
        hstate[reg] = hn;
        stg[((colL2>>3)*32u + rloc)*8u + (colL2&7u)] = (bf16)hn;
      }
    }
    __syncthreads();
    { size_t blk = ((size_t)(par*8u + r)*16u + c)*1024u;
      unsigned long long v = *(const unsigned long long*)(stg + (size_t)tid*4u);
      if (l2m)
        __hip_atomic_store((unsigned long long*)(hbuf + blk + (size_t)tid*4u), v,
                           __ATOMIC_RELAXED, __HIP_MEMORY_SCOPE_WORKGROUP);
      else
        __hip_atomic_store((unsigned long long*)(hbuf + blk + (size_t)tid*4u), v,
                           __ATOMIC_RELAXED, __HIP_MEMORY_SCOPE_AGENT); }
    if (l2m) rb_bar_l2 (l2f, tid, lane, wave, c, kb + 2u);
    else     rb_bar_llc(rb,  tid, lane, wave, c, kb + 7u);
    // gather full h_new for own rows into hA (consumed by P3 + next P1)
    if (l2m) {
      const char* hb = (const char*)hbuf + (size_t)(par*8u + r)*32768u
                       + (size_t)tid*16u;
      u32x4 g[8];
      #pragma unroll
      for (int i=0;i<8;i++) g[i] = ld_u128_sc0(hb + i*4096);
      vm_wait0();
      #pragma unroll
      for (int i=0;i<8;i++) ((u32x4*)hA)[tid + 256u*i] = g[i];
    } else {
      unsigned long long* s = (unsigned long long*)(hbuf + ((size_t)(par*8u + r)*16u)*1024u);
      unsigned long long* d = (unsigned long long*)hA;
      unsigned long long gtmp[16];
      #pragma unroll
      for (int i=0;i<16;i++)
        gtmp[i] = __hip_atomic_load(s + tid + 256u*i,
                                    __ATOMIC_RELAXED, __HIP_MEMORY_SCOPE_AGENT);
      #pragma unroll
      for (int i=0;i<16;i++) d[tid + 256u*i] = gtmp[i];
    }
    __syncthreads();

    // ================= phase 3: dp = h_new@W_d, sample, outputs =========
    f32x4 dp00={0.f,0.f,0.f,0.f}, dp01={0.f,0.f,0.f,0.f};
    f32x4 dp10={0.f,0.f,0.f,0.f}, dp11={0.f,0.f,0.f,0.f};
    #pragma unroll
    for (int kc=0;kc<16;kc++) {
      bf16x8 a0 = *(const bf16x8*)(hA + (((unsigned)kc*4u+q)*32u + m)*8u);
      bf16x8 a1 = *(const bf16x8*)(hA + (((unsigned)kc*4u+q)*32u + 16u + m)*8u);
      dp00 = mfma16(a0, wd[kc][0], dp00);
      dp01 = mfma16(a0, wd[kc][1], dp01);
      dp10 = mfma16(a1, wd[kc][0], dp10);
      dp11 = mfma16(a1, wd[kc][1], dp11);
    }
    if (wave < 2u) {   // mu cols 0..63 -> muS (bf16)
      #pragma unroll
      for (int reg=0;reg<4;reg++) {
        unsigned r0 = 4u*q + (unsigned)reg;
        muS[r0*64u + wave*32u + m]              = (bf16)(dp00[reg] + bd0);
        muS[r0*64u + wave*32u + 16u + m]        = (bf16)(dp01[reg] + bd1);
        muS[(r0+16u)*64u + wave*32u + m]        = (bf16)(dp10[reg] + bd0);
        muS[(r0+16u)*64u + wave*32u + 16u + m]  = (bf16)(dp11[reg] + bd1);
      }
    } else {           // raw cols 64..127 -> rawS (fp32)
      unsigned cb = (wave - 2u)*32u;
      #pragma unroll
      for (int reg=0;reg<4;reg++) {
        unsigned r0 = 4u*q + (unsigned)reg;
        rawS[r0*64u + cb + m]              = dp00[reg] + bd0;
        rawS[r0*64u + cb + 16u + m]        = dp01[reg] + bd1;
        rawS[(r0+16u)*64u + cb + m]        = dp10[reg] + bd0;
        rawS[(r0+16u)*64u + cb + 16u + m]  = dp11[reg] + bd1;
      }
    }
    __syncthreads();
    {
      bf16x8 mu8 = *(const bf16x8*)(muS + (size_t)zrow*64u + zi*8u);
      f32x4 rw0 = *(const f32x4*)(rawS + (size_t)zrow*64u + zi*8u);
      f32x4 rw1 = *(const f32x4*)(rawS + (size_t)zrow*64u + zi*8u + 4u);
      float ent = 0.f, lp = 0.f;
      float zf[8];
      #pragma unroll
      for (int j=0;j<8;j++) {
        float raw = (j < 4) ? rw0[j] : rw1[j-4];
        float sp = (raw > 20.f) ? raw : __logf(1.f + __expf(raw));
        sp += 1e-4f;
        float ls = __logf(sp);
        float e = (j < 4) ? eps0[j] : eps1[j-4];
        float zv = (float)mu8[j] + sp*e;
        zf[j] = zv;
        ent += ls;
        lp  -= 0.5f*e*e + ls;
      }
      ent += 8.f*1.4189385332046727f;
      lp  -= 8.f*0.9189385332046727f;
      bf16x8 zb;
      #pragma unroll
      for (int j=0;j<8;j++) zb[j] = (bf16)zf[j];
      *(bf16x8*)(zA + ((size_t)zi*32u + zrow)*8u) = zb;
      // output stores distributed across the 16 col-WGs (2 rows each)
      if ((zrow>>1) == c) {
        float* zo = out + ((size_t)(rowG0 + zrow)*1024u + t)*64u + zi*8u;
        f32x4 o0 = {zf[0],zf[1],zf[2],zf[3]}, o1 = {zf[4],zf[5],zf[6],zf[7]};
        *(f32x4*)zo = o0; *((f32x4*)zo + 1) = o1;
        if (t == tend - 1u)  // carry z across chunk boundary
          *(bf16x8*)(zbuf + ((size_t)(rowG0 + zrow)*64u + zi*8u)) = zb;
      }
      ent += __shfl_down(ent, 4); lp += __shfl_down(lp, 4);
      ent += __shfl_down(ent, 2); lp += __shfl_down(lp, 2);
      ent += __shfl_down(ent, 1); lp += __shfl_down(lp, 1);
      if (zi == 0u && (zrow>>1) == c) {
        out[16777216u + (size_t)(rowG0 + zrow)*1024u + t] = ent;
        out[17039360u + (size_t)(rowG0 + zrow)*1024u + t] = lp;
      }
    }
    __syncthreads();
  }
}

// ------------------------------- host --------------------------------------
extern "C" void kernel_launch(void* const* d_in, const int* in_sizes, int n_in,
                              void* d_out, int out_size, void* d_ws, size_t ws_size,
                              hipStream_t stream)
{
  const float* x     = (const float*)d_in[0];
  const float* noise = (const float*)d_in[1];
  const float* W_x   = (const float*)d_in[2];
  const float* W_h   = (const float*)d_in[3];
  const float* bias  = (const float*)d_in[4];
  const float* W_d   = (const float*)d_in[5];
  const float* b_d   = (const float*)d_in[6];
  float* out = (float*)d_out;
  char* ws = (char*)d_ws;

  size_t off = 0;
  unsigned* bar = (unsigned*)(ws + off);  off += 262144;  // 16ch x 8rb x 2KB
  bf16* Wdf  = (bf16*)(ws + off);         off += 65536ull*2;
  bf16* Whs  = (bf16*)(ws + off);         off += 786432ull*2;
  bf16* Wxz  = (bf16*)(ws + off);         off += 98304ull*2;
  bf16* Wxx  = (bf16*)(ws + off);         off += 393216ull*2;
  bf16* hbuf = (bf16*)(ws + off);         off += 262144ull*2;
  bf16* ubuf = (bf16*)(ws + off);         off += 262144ull*2;
  bf16* zbuf = (bf16*)(ws + off);         off += 16384ull*2;
  bf16* xT   = (bf16*)(ws + off);         off += 16777216ull*2;
  bf16* xgx  = (bf16*)(ws + off);         // tlen*16*64*96 bf16 (chunked)
  size_t fixed = off;

  unsigned tlen = 1024;
  while (tlen > 64 && fixed + (size_t)tlen*196608ull > ws_size) tlen >>= 1;
  unsigned nch = 1024/tlen;

  hipMemsetAsync(bar, 0, 262144, stream);
  repack_kernel<<<5248, 256, 0, stream>>>(W_x, W_h, W_d, Whs, Wxz, Wdf, Wxx);
  xpose_kernel<<<1024, 256, 0, stream>>>(x, xT);
  hipFuncSetAttribute((const void*)rec_kernel,
                      hipFuncAttributeMaxDynamicSharedMemorySize, LDS_REC);
  for (unsigned ch = 0; ch < nch; ++ch) {
    unsigned t0 = ch*tlen;
    xgx_kernel<<<tlen*16, 256, 0, stream>>>(xT, Wxx, bias, xgx, t0);
    rec_kernel<<<NWG, 256, LDS_REC, stream>>>(Whs, Wxz, Wdf, xgx, noise, b_d,
                                              out, hbuf, ubuf, zbuf,
                                              bar + (size_t)ch*4096u, t0, tlen);
  }
}

// Round 5
// 8979.170 us; speedup vs baseline: 1.7317x; 1.0035x over previous
//
#include <hip/hip_runtime.h>
#include <stdint.h>

// ---------------------------------------------------------------------------
// RnnInferenceNetwork: GRU-variant scan, T=1024, SB=256 rows, H=512, L=64.
// Design: 128 persistent wgs (8 row-blocks x 16 col-groups), weights resident
// in LDS (W_h/W_xz slices) + VGPRs (W_d frags). x@W_x precomputed (bf16 MFMA).
// R3: per-row-block 16-WG flag barriers. R4: fence-free LLC exchange.
// R5/R6: XCD-local exchange through the shared L2 (plain stores + sc0 loads),
// gated by an on-device self-test (falls back to the proven LLC path).
// R7: (1) NON-TEMPORAL loads for xgx/noise and nt stores for outputs/xgx ->
//     streaming operands no longer evict the hbuf/ubuf/flag working set from
//     the XCD L2 (R6 counters: WRITE_SIZE 600MB = L2 writebacks of exchange
//     lines, FETCH 698MB incl. их re-fetch from MALL on the critical path);
//     (2) flag publish via atomic swap (executes at TCC atomic unit, skips
//     the store/WC path); (3) all-wave flag polling, post-poll sync dropped.
// ---------------------------------------------------------------------------

#define NWG  128u

typedef __bf16 bf16;
typedef __attribute__((ext_vector_type(8))) __bf16 bf16x8;
typedef __attribute__((ext_vector_type(8))) short  s16x8;
typedef __attribute__((ext_vector_type(4))) float  f32x4;
typedef __attribute__((ext_vector_type(4))) unsigned int u32x4;
typedef __attribute__((ext_vector_type(2))) unsigned long long u64x2;

__device__ __forceinline__ f32x4 mfma16(bf16x8 a, bf16x8 b, f32x4 c) {
  return __builtin_amdgcn_mfma_f32_16x16x32_bf16(
      __builtin_bit_cast(s16x8, a), __builtin_bit_cast(s16x8, b), c, 0, 0, 0);
}

// ---- sc0 load helpers: bypass L1, serviced by the XCD-local L2 ------------
__device__ __forceinline__ unsigned ld_u32_sc0(const unsigned* p) {
  unsigned v;
  asm volatile("global_load_dword %0, %1, off sc0\n\ts_waitcnt vmcnt(0)"
               : "=v"(v) : "v"(p) : "memory");
  return v;
}
__device__ __forceinline__ u32x4 ld_u128_sc0(const void* p) {
  u32x4 v;
  asm volatile("global_load_dwordx4 %0, %1, off sc0" : "=v"(v) : "v"(p));
  return v;
}
__device__ __forceinline__ void vm_wait0() {
  asm volatile("s_waitcnt vmcnt(0)" ::: "memory");
  __builtin_amdgcn_sched_barrier(0);   // keep consumers after the wait
}

// --------------------------- repack weights --------------------------------
// B-fragment layout: [kc][q][n][j] ; element = W[k = kc*32+q*8+j][col(n)]
// Whs: [c16][kc16][q4][n96][j8]   col = (n/32)*512 + 32c + (n%32)   (W_h)
// Wxz: [c16][kc2 ][q4][n96][j8]   same col, rows 256..319 of W_x
// Wdf: [kc16][q4][n128][j8]       col = n                            (W_d)
// Wxx: [c16][kc8 ][q4][n96][j8]   same col, rows 0..255 of W_x
__global__ void repack_kernel(const float* __restrict__ W_x,
                              const float* __restrict__ W_h,
                              const float* __restrict__ W_d,
                              bf16* __restrict__ Whs, bf16* __restrict__ Wxz,
                              bf16* __restrict__ Wdf, bf16* __restrict__ Wxx)
{
  unsigned e = blockIdx.x*256u + threadIdx.x;
  if (e < 786432u) {
    unsigned c = e/49152u, r0 = e%49152u;
    unsigned kc = r0/3072u, r1 = r0%3072u;
    unsigned q = r1/768u, r2 = r1%768u;
    unsigned n = r2/8u, j = r2%8u;
    unsigned k = kc*32u + q*8u + j;
    unsigned colg = (n>>5)*512u + c*32u + (n&31u);
    Whs[e] = (bf16)W_h[k*1536u + colg];
  } else if (e < 884736u) {
    unsigned e1 = e - 786432u;
    unsigned c = e1/6144u, r0 = e1%6144u;
    unsigned kc = r0/3072u, r1 = r0%3072u;
    unsigned q = r1/768u, r2 = r1%768u;
    unsigned n = r2/8u, j = r2%8u;
    unsigned k = 256u + kc*32u + q*8u + j;
    unsigned colg = (n>>5)*512u + c*32u + (n&31u);
    Wxz[e1] = (bf16)W_x[k*1536u + colg];
  } else if (e < 950272u) {
    unsigned e2 = e - 884736u;
    unsigned kc = e2/4096u, r0 = e2%4096u;
    unsigned q = r0/1024u, r1 = r0%1024u;
    unsigned n = r1/8u, j = r1%8u;
    unsigned k = kc*32u + q*8u + j;
    Wdf[e2] = (bf16)W_d[k*128u + n];
  } else if (e < 1343488u) {
    unsigned e3 = e - 950272u;
    unsigned c = e3/24576u, r0 = e3%24576u;
    unsigned kc = r0/3072u, r1 = r0%3072u;
    unsigned q = r1/768u, r2 = r1%768u;
    unsigned n = r2/8u, j = r2%8u;
    unsigned k = kc*32u + q*8u + j;
    unsigned colg = (n>>5)*512u + c*32u + (n&31u);
    Wxx[e3] = (bf16)W_x[k*1536u + colg];
  }
}

// ----------------- transpose x [B][T][D] f32 -> xT [t][b][d] bf16 ----------
__global__ void xpose_kernel(const float* __restrict__ x, bf16* __restrict__ xT)
{
  unsigned t = blockIdx.x, tid = threadIdx.x;
  unsigned row = tid>>2, seg = tid&3u;
  const float* src = x + ((size_t)row*1024u + t)*256u + seg*64u;
  bf16* dst = xT + (size_t)t*16384u + row*256u + seg*64u;
  #pragma unroll
  for (int i = 0; i < 8; ++i) {
    f32x4 v0 = *(const f32x4*)(src + i*8);
    f32x4 v1 = *(const f32x4*)(src + i*8 + 4);
    bf16x8 o;
    #pragma unroll
    for (int j = 0; j < 4; ++j) { o[j] = (bf16)v0[j]; o[4+j] = (bf16)v1[j]; }
    *(bf16x8*)(dst + i*8) = o;
  }
}

// --------- xg_x precompute: xgx[lt][c][b64][n96] = x@W_x[:256]+b (bf16) ----
__global__ void __launch_bounds__(256) xgx_kernel(const bf16* __restrict__ xT,
                                                  const bf16* __restrict__ Wxx,
                                                  const float* __restrict__ bias,
                                                  bf16* __restrict__ xgx,
                                                  unsigned t0)
{
  __shared__ bf16 WxS[24576];
  __shared__ bf16 otile[6144];
  unsigned bid = blockIdx.x, lt = bid>>4, c = bid&15u, tid = threadIdx.x;
  unsigned t = t0 + lt;
  { const u32x4* s = (const u32x4*)(Wxx + (size_t)c*24576u); u32x4* d = (u32x4*)WxS;
    #pragma unroll
    for (int i=0;i<12;i++) d[tid+256u*i] = s[tid+256u*i]; }
  __syncthreads();
  unsigned wave = tid>>6, lane = tid&63u, q = lane>>4, m = lane&15u;
  f32x4 zero4 = {0.f,0.f,0.f,0.f};
  f32x4 acc[6];
  #pragma unroll
  for (int nt=0;nt<6;nt++) acc[nt] = zero4;
  const bf16* ap = xT + (size_t)t*16384u + (16u*wave + m)*256u + q*8u;
  #pragma unroll
  for (int kc=0;kc<8;kc++) {
    bf16x8 a = *(const bf16x8*)(ap + kc*32);
    #pragma unroll
    for (int nt=0;nt<6;nt++) {
      bf16x8 bb = *(const bf16x8*)(WxS + (((unsigned)kc*4u+q)*96u + (unsigned)nt*16u + m)*8u);
      acc[nt] = mfma16(a, bb, acc[nt]);
    }
  }
  #pragma unroll
  for (int nt=0;nt<6;nt++) {
    unsigned n = (unsigned)nt*16u + m;
    unsigned colg = (n>>5)*512u + c*32u + (n&31u);
    float bv = bias[colg];
    #pragma unroll
    for (int reg=0;reg<4;reg++)
      otile[(16u*wave + 4u*q + (unsigned)reg)*96u + n] = (bf16)(acc[nt][reg] + bv);
  }
  __syncthreads();
  { u32x4* d = (u32x4*)(xgx + (size_t)(lt*16u + c)*6144u);
    const u32x4* s = (const u32x4*)otile;
    #pragma unroll
    for (int i=0;i<3;i++) __builtin_nontemporal_store(s[tid+256u*i], d+tid+256u*i); }
}

// ------------------- per-row-block barriers (16 WGs) -----------------------
// LLC variant (R4, proven): agent-scope cache-bypassing atomics; no fence
// needed because every cross-WG byte moves via agent atomics on both sides.
__device__ __forceinline__ void rb_bar_llc(unsigned* __restrict__ flags,
                                           unsigned tid, unsigned lane,
                                           unsigned wave, unsigned c,
                                           unsigned target)
{
  __syncthreads();   // drains vmcnt -> all wg data stores visible at LLC
  if (tid == 0)
    __hip_atomic_store(&flags[c], target, __ATOMIC_RELAXED,
                       __HIP_MEMORY_SCOPE_AGENT);
  if (wave == 0) {
    for (;;) {
      unsigned v = target;
      if (lane < 16u)
        v = __hip_atomic_load(&flags[lane], __ATOMIC_RELAXED,
                              __HIP_MEMORY_SCOPE_AGENT);
      if (__all((int)(v >= target))) break;
      __builtin_amdgcn_s_sleep(1);
    }
  }
  __syncthreads();
}
// L2 variant: all 16 WGs runtime-verified on one XCD with working sc0
// semantics. R7: flag publish = atomic swap (executes at the TCC atomic
// unit, no store-path latency); ALL waves poll independently with sc0 loads
// -> no post-poll __syncthreads (surrounding syncs order all LDS sharing).
__device__ __forceinline__ void rb_bar_l2(unsigned* __restrict__ flags,
                                          unsigned tid, unsigned lane,
                                          unsigned c, unsigned target)
{
  __syncthreads();   // drains vmcnt -> all wg data stores ack'd at L2
  if (tid == 0)
    (void)__hip_atomic_exchange(&flags[c], target, __ATOMIC_RELAXED,
                                __HIP_MEMORY_SCOPE_WORKGROUP);
  for (;;) {
    unsigned v = target;
    if (lane < 16u) v = ld_u32_sc0(&flags[lane]);
    if (__all((int)(v >= target))) break;
  }
}

// ------------------------------ recurrent kernel ---------------------------
// grid = 128: r = blockIdx%8 (row-block of 32 rows; %8 -> one XCD under
// round-robin dispatch), c = blockIdx/8 (h-cols [32c,32c+32)). LDS overlay
// (12288 B): phases 1-2 use stg(2KB)+zgSf(4KB); phase 3 muS(4KB)+rawS(8KB).
// bar region per row-block: 512 u32 (2 KB):
//   [0..15] LLC flags | [32..47] xcd ids | [64..79] L2 flags |
//   [96..111] selftest verdicts | [128..383] selftest slots (256 u32)
#define LDS_REC 159744
__global__ void __launch_bounds__(256, 1) rec_kernel(
    const bf16* __restrict__ Whs_g, const bf16* __restrict__ Wxz_g,
    const bf16* __restrict__ Wdf_g, const bf16* __restrict__ xgx,
    const float* __restrict__ noise, const float* __restrict__ b_d,
    float* __restrict__ out, bf16* __restrict__ hbuf, bf16* __restrict__ ubuf,
    bf16* __restrict__ zbuf, unsigned* __restrict__ bar,
    unsigned t0, unsigned tlen)
{
  extern __shared__ char smem[];
  bf16*  WhS  = (bf16*)(smem);            // 49152 el = 98304 B
  bf16*  WxzS = (bf16*)(smem + 98304);    // 6144 el = 12288 B
  bf16*  hA   = (bf16*)(smem + 110592);   // 16384 el  [kc16][q4][row32][j8]
  bf16*  zA   = (bf16*)(smem + 143360);   // 2048 el   [kc2][q4][row32][j8]
  bf16*  stg  = (bf16*)(smem + 147456);   // 1024 el   [q4][row32][j8]
  float* zgSf = (float*)(smem + 149504);  // 1024 el   [row32][col32] fp32
  bf16*  muS  = (bf16*)(smem + 147456);   // 2048 el   [row32][col64] (overlay)
  float* rawS = (float*)(smem + 151552);  // 2048 el   [row32][col64] fp32

  const unsigned tid = threadIdx.x;
  const unsigned wave = tid>>6, lane = tid&63u, q = lane>>4, m = lane&15u;
  const unsigned mt = wave&1u, gt = wave>>1;   // ph1: gate gt; ph2: N-tile gt
  const unsigned r = blockIdx.x & 7u, c = blockIdx.x >> 3;   // R5 remap
  const unsigned b0 = (r&1u)*32u;
  const unsigned rowG0 = r*32u;
  const unsigned zrow = tid>>3, zi = tid&7u;
  unsigned* rb = bar + (size_t)r*512u;

  // ---- stage resident weights ----
  { const u32x4* s = (const u32x4*)(Whs_g + (size_t)c*49152u); u32x4* d = (u32x4*)WhS;
    #pragma unroll
    for (int i=0;i<24;i++) d[tid+256u*i] = s[tid+256u*i]; }
  { const u32x4* s = (const u32x4*)(Wxz_g + (size_t)c*6144u); u32x4* d = (u32x4*)WxzS;
    #pragma unroll
    for (int i=0;i<3;i++) d[tid+256u*i] = s[tid+256u*i]; }
  // ---- W_d fragments in VGPRs (cols [32*wave, 32*wave+32)) ----
  bf16x8 wd[16][2];
  #pragma unroll
  for (int kc=0;kc<16;kc++) {
    #pragma unroll
    for (int nw=0;nw<2;nw++)
      wd[kc][nw] = *(const bf16x8*)(Wdf_g +
          ((((unsigned)kc*4u+q)*128u + wave*32u + (unsigned)nw*16u + m)*8u));
  }
  float bd0 = b_d[wave*32u + m], bd1 = b_d[wave*32u + 16u + m];

  // =================== R6 self-testing XCD handshake =====================
  bool l2m;
  {
    unsigned* ts = rb + 128u;          // 256-word test slots
    unsigned myxcd;
    asm volatile("s_getreg_b32 %0, hwreg(HW_REG_XCC_ID)" : "=s"(myxcd));
    myxcd = (myxcd & 15u) + 1u;
    if (tid == 0)
      __hip_atomic_store(&rb[32u + c], myxcd, __ATOMIC_RELAXED,
                         __HIP_MEMORY_SCOPE_AGENT);
    rb_bar_llc(rb, tid, lane, wave, c, 1u);
    bool xcdok;
    { unsigned v = myxcd;
      if (lane < 16u)
        v = __hip_atomic_load(&rb[32u + lane], __ATOMIC_RELAXED,
                              __HIP_MEMORY_SCOPE_AGENT);
      xcdok = (bool)__all((int)(v == myxcd));
    }
    // pattern A: plain (workgroup-scope) stores, exactly like loop data path
    if (tid < 16u)
      __hip_atomic_store(&ts[c*16u + tid], 0xA0000000u + (c<<8) + tid,
                         __ATOMIC_RELAXED, __HIP_MEMORY_SCOPE_WORKGROUP);
    rb_bar_llc(rb, tid, lane, wave, c, 2u);
    unsigned jj = tid>>4, ii = tid&15u;
    bool okA = (ld_u32_sc0(&ts[tid]) == 0xA0000000u + (jj<<8) + ii);
    rb_bar_llc(rb, tid, lane, wave, c, 3u);   // reads done before overwrite
    // pattern B: rewrite the SAME lines; re-read from the SAME threads ->
    // detects stale-L1 on sc0 (the deadlock mode)
    if (tid < 16u)
      __hip_atomic_store(&ts[c*16u + tid], 0xB0000000u + (c<<8) + tid,
                         __ATOMIC_RELAXED, __HIP_MEMORY_SCOPE_WORKGROUP);
    rb_bar_llc(rb, tid, lane, wave, c, 4u);
    bool okB = (ld_u32_sc0(&ts[tid]) == 0xB0000000u + (jj<<8) + ii);
    // WG-wide AND via LDS scratch
    unsigned* sc = (unsigned*)stg;
    sc[0] = 1u; __syncthreads();
    if (!(okA && okB)) sc[0] = 0u;
    __syncthreads();
    unsigned myok = (sc[0] != 0u) ? 1u : 2u;
    __syncthreads();
    if (tid == 0)
      __hip_atomic_store(&rb[96u + c], myok, __ATOMIC_RELAXED,
                         __HIP_MEMORY_SCOPE_AGENT);
    rb_bar_llc(rb, tid, lane, wave, c, 5u);
    { unsigned v = 1u;
      if (lane < 16u)
        v = __hip_atomic_load(&rb[96u + lane], __ATOMIC_RELAXED,
                              __HIP_MEMORY_SCOPE_AGENT);
      l2m = xcdok && (bool)__all((int)(v == 1u));
    }
  }
  unsigned* l2f = rb + 64u;

  // ---- init state ----
  float hstate[4];   // fp32 carry of own h tile: rows 16mt+4q+reg, col gt*16+m
  if (t0 == 0) {
    u32x4 zz = {0,0,0,0};
    u32x4* d = (u32x4*)hA;
    #pragma unroll
    for (int i=0;i<8;i++) d[tid+256u*i] = zz;
    ((u32x4*)zA)[tid] = zz;
    #pragma unroll
    for (int reg=0;reg<4;reg++) hstate[reg] = 0.f;
    __syncthreads();
  } else {
    // written by the PREVIOUS dispatch (kernel-boundary flush gives visibility)
    const u32x4* s = (const u32x4*)(hbuf + ((size_t)(1u*8u + r)*16u)*1024u); // parity 1
    u32x4* d = (u32x4*)hA;
    #pragma unroll
    for (int i=0;i<8;i++) d[tid+256u*i] = s[tid+256u*i];
    bf16x8 zv = *(const bf16x8*)(zbuf + ((size_t)(rowG0 + zrow)*64u + zi*8u));
    *(bf16x8*)(zA + ((size_t)zi*32u + zrow)*8u) = zv;
    __syncthreads();
    unsigned cl = gt*16u + m;
    #pragma unroll
    for (int reg=0;reg<4;reg++)
      hstate[reg] = (float)hA[((c*4u + (cl>>3))*32u + 16u*mt + 4u*q + (unsigned)reg)*8u + (cl&7u)];
  }

  const unsigned tend = t0 + tlen;
  for (unsigned t = t0; t < tend; ++t) {
    unsigned par = t & 1u;
    unsigned kb = 2u*(t - t0);
    // ---- early global loads: NON-TEMPORAL (R7) -> no L2 allocation, the
    // exchange working set stays L2-resident ----
    __bf16 xv1[2][4]; __bf16 xv2[4];
    { size_t base = ((size_t)((t - t0)*16u + c)*64u + b0 + 16u*mt + 4u*q)*96u + m;
      #pragma unroll
      for (int nt=0;nt<2;nt++)
        #pragma unroll
        for (int reg=0;reg<4;reg++)
          xv1[nt][reg] = __builtin_nontemporal_load(
              &xgx[base + (unsigned)reg*96u + gt*32u + (unsigned)nt*16u]);
      #pragma unroll
      for (int reg=0;reg<4;reg++)
        xv2[reg] = __builtin_nontemporal_load(
            &xgx[base + (unsigned)reg*96u + 64u + gt*16u]);
    }
    f32x4 eps0, eps1;
    { const f32x4* np4 = (const f32x4*)(noise + ((size_t)t*256u + rowG0 + zrow)*64u + zi*8u);
      eps0 = __builtin_nontemporal_load(np4);
      eps1 = __builtin_nontemporal_load(np4 + 1); }

    // ================= phase 1: z/r gates, u = r*h =================
    f32x4 accP0 = {0.f,0.f,0.f,0.f}, accP1 = {0.f,0.f,0.f,0.f};
    #pragma unroll
    for (int kc=0;kc<2;kc++) {
      bf16x8 a = *(const bf16x8*)(zA + (((unsigned)kc*4u+q)*32u + 16u*mt + m)*8u);
      accP0 = mfma16(a, *(const bf16x8*)(WxzS + (((unsigned)kc*4u+q)*96u + gt*32u + m)*8u), accP0);
      accP1 = mfma16(a, *(const bf16x8*)(WxzS + (((unsigned)kc*4u+q)*96u + gt*32u + 16u + m)*8u), accP1);
    }
    #pragma unroll
    for (int kc=0;kc<16;kc++) {
      bf16x8 a = *(const bf16x8*)(hA + (((unsigned)kc*4u+q)*32u + 16u*mt + m)*8u);
      accP0 = mfma16(a, *(const bf16x8*)(WhS + (((unsigned)kc*4u+q)*96u + gt*32u + m)*8u), accP0);
      accP1 = mfma16(a, *(const bf16x8*)(WhS + (((unsigned)kc*4u+q)*96u + gt*32u + 16u + m)*8u), accP1);
    }
    #pragma unroll
    for (int reg=0;reg<4;reg++) {
      unsigned rloc = 16u*mt + 4u*q + (unsigned)reg;
      float g0 = accP0[reg] + (float)xv1[0][reg];
      float g1 = accP1[reg] + (float)xv1[1][reg];
      float s0 = 1.f/(1.f + __expf(-g0));
      float s1 = 1.f/(1.f + __expf(-g1));
      if (gt == 0) {          // z-gate -> zgSf (fp32)
        zgSf[rloc*32u + m]       = s0;
        zgSf[rloc*32u + 16u + m] = s1;
      } else {                // r-gate -> u = r*h staged frag-major
        unsigned cl0 = m, cl1 = 16u + m;
        float h0 = (float)hA[((c*4u + (cl0>>3))*32u + rloc)*8u + (cl0&7u)];
        float h1 = (float)hA[((c*4u + (cl1>>3))*32u + rloc)*8u + (cl1&7u)];
        stg[((cl0>>3)*32u + rloc)*8u + (cl0&7u)] = (bf16)(s0*h0);
        stg[((cl1>>3)*32u + rloc)*8u + (cl1&7u)] = (bf16)(s1*h1);
      }
    }
    __syncthreads();
    // u slice -> ubuf
    { size_t blk = ((size_t)(par*8u + r)*16u + c)*1024u;
      unsigned long long v = *(const unsigned long long*)(stg + (size_t)tid*4u);
      if (l2m)
        __hip_atomic_store((unsigned long long*)(ubuf + blk + (size_t)tid*4u), v,
                           __ATOMIC_RELAXED, __HIP_MEMORY_SCOPE_WORKGROUP);
      else
        __hip_atomic_store((unsigned long long*)(ubuf + blk + (size_t)tid*4u), v,
                           __ATOMIC_RELAXED, __HIP_MEMORY_SCOPE_AGENT); }
    if (l2m) rb_bar_l2 (l2f, tid, lane, c, kb + 1u);
    else     rb_bar_llc(rb,  tid, lane, wave, c, kb + 6u);

    // ================= phase 2: n_cand, h_new =================
    // u MFMA A-fragments loaded DIRECTLY (no gather): ubuf slice layout
    // [q4][row32][j8] == fragment layout; 16B per lane per c-slice.
    bf16x8 ufr[16];
    if (l2m) {
      const char* ub = (const char*)ubuf + (size_t)(par*8u + r)*32768u
                       + (q*32u + 16u*mt + m)*16u;
      u32x4 tmp[16];
      #pragma unroll
      for (int kc=0;kc<16;kc++) tmp[kc] = ld_u128_sc0(ub + kc*2048);
      vm_wait0();
      #pragma unroll
      for (int kc=0;kc<16;kc++) ufr[kc] = __builtin_bit_cast(bf16x8, tmp[kc]);
    } else {
      unsigned long long* ubp = (unsigned long long*)ubuf;
      size_t b64 = ((size_t)(par*8u + r)*16u)*256u + (q*32u + 16u*mt + m)*2u;
      #pragma unroll
      for (int kc=0;kc<16;kc++) {
        unsigned long long a0 = __hip_atomic_load(ubp + b64 + (unsigned)kc*256u,
                                    __ATOMIC_RELAXED, __HIP_MEMORY_SCOPE_AGENT);
        unsigned long long a1 = __hip_atomic_load(ubp + b64 + (unsigned)kc*256u + 1u,
                                    __ATOMIC_RELAXED, __HIP_MEMORY_SCOPE_AGENT);
        u64x2 tt; tt[0] = a0; tt[1] = a1;
        ufr[kc] = __builtin_bit_cast(bf16x8, tt);
      }
    }
    // n preact = xg_n(x part, xv2) + z_prev@W_x[D:,2H:] + (r*h)@W_h[:,2H:]
    f32x4 accNa = {0.f,0.f,0.f,0.f}, accNb = {0.f,0.f,0.f,0.f};
    #pragma unroll
    for (int kc=0;kc<2;kc++) {   // z_prev contribution (zA in LDS)
      bf16x8 a = *(const bf16x8*)(zA + (((unsigned)kc*4u+q)*32u + 16u*mt + m)*8u);
      accNa = mfma16(a, *(const bf16x8*)(WxzS + (((unsigned)kc*4u+q)*96u + 64u + gt*16u + m)*8u), accNa);
    }
    #pragma unroll
    for (int kc=0;kc<16;kc++) {
      f32x4& acc = (kc & 1) ? accNb : accNa;
      acc = mfma16(ufr[kc], *(const bf16x8*)(WhS + (((unsigned)kc*4u+q)*96u + 64u + gt*16u + m)*8u), acc);
    }
    { unsigned colL2 = gt*16u + m;
      #pragma unroll
      for (int reg=0;reg<4;reg++) {
        unsigned rloc = 16u*mt + 4u*q + (unsigned)reg;
        float zg = zgSf[rloc*32u + colL2];
        float pre = accNa[reg] + accNb[reg] + (float)xv2[reg];
        float e2 = __expf(2.f*pre);
        float nc = 1.f - 2.f/(e2 + 1.f);
        float hn = (1.f - zg)*nc + zg*hstate[reg];   // fp32 state carry
        hstate[reg] = hn;
        stg[((colL2>>3)*32u + rloc)*8u + (colL2&7u)] = (bf16)hn;
      }
    }
    __syncthreads();
    { size_t blk = ((size_t)(par*8u + r)*16u + c)*1024u;
      unsigned long long v = *(const unsigned long long*)(stg + (size_t)tid*4u);
      if (l2m)
        __hip_atomic_store((unsigned long long*)(hbuf + blk + (size_t)tid*4u), v,
                           __ATOMIC_RELAXED, __HIP_MEMORY_SCOPE_WORKGROUP);
      else
        __hip_atomic_store((unsigned long long*)(hbuf + blk + (size_t)tid*4u), v,
                           __ATOMIC_RELAXED, __HIP_MEMORY_SCOPE_AGENT); }
    if (l2m) rb_bar_l2 (l2f, tid, lane, c, kb + 2u);
    else     rb_bar_llc(rb,  tid, lane, wave, c, kb + 7u);
    // gather full h_new for own rows into hA (consumed by P3 + next P1)
    if (l2m) {
      const char* hb = (const char*)hbuf + (size_t)(par*8u + r)*32768u
                       + (size_t)tid*16u;
      u32x4 g[8];
      #pragma unroll
      for (int i=0;i<8;i++) g[i] = ld_u128_sc0(hb + i*4096);
      vm_wait0();
      #pragma unroll
      for (int i=0;i<8;i++) ((u32x4*)hA)[tid + 256u*i] = g[i];
    } else {
      unsigned long long* s = (unsigned long long*)(hbuf + ((size_t)(par*8u + r)*16u)*1024u);
      unsigned long long* d = (unsigned long long*)hA;
      unsigned long long gtmp[16];
      #pragma unroll
      for (int i=0;i<16;i++)
        gtmp[i] = __hip_atomic_load(s + tid + 256u*i,
                                    __ATOMIC_RELAXED, __HIP_MEMORY_SCOPE_AGENT);
      #pragma unroll
      for (int i=0;i<16;i++) d[tid + 256u*i] = gtmp[i];
    }
    __syncthreads();

    // ================= phase 3: dp = h_new@W_d, sample, outputs =========
    f32x4 dp00={0.f,0.f,0.f,0.f}, dp01={0.f,0.f,0.f,0.f};
    f32x4 dp10={0.f,0.f,0.f,0.f}, dp11={0.f,0.f,0.f,0.f};
    #pragma unroll
    for (int kc=0;kc<16;kc++) {
      bf16x8 a0 = *(const bf16x8*)(hA + (((unsigned)kc*4u+q)*32u + m)*8u);
      bf16x8 a1 = *(const bf16x8*)(hA + (((unsigned)kc*4u+q)*32u + 16u + m)*8u);
      dp00 = mfma16(a0, wd[kc][0], dp00);
      dp01 = mfma16(a0, wd[kc][1], dp01);
      dp10 = mfma16(a1, wd[kc][0], dp10);
      dp11 = mfma16(a1, wd[kc][1], dp11);
    }
    if (wave < 2u) {   // mu cols 0..63 -> muS (bf16)
      #pragma unroll
      for (int reg=0;reg<4;reg++) {
        unsigned r0 = 4u*q + (unsigned)reg;
        muS[r0*64u + wave*32u + m]              = (bf16)(dp00[reg] + bd0);
        muS[r0*64u + wave*32u + 16u + m]        = (bf16)(dp01[reg] + bd1);
        muS[(r0+16u)*64u + wave*32u + m]        = (bf16)(dp10[reg] + bd0);
        muS[(r0+16u)*64u + wave*32u + 16u + m]  = (bf16)(dp11[reg] + bd1);
      }
    } else {           // raw cols 64..127 -> rawS (fp32)
      unsigned cb = (wave - 2u)*32u;
      #pragma unroll
      for (int reg=0;reg<4;reg++) {
        unsigned r0 = 4u*q + (unsigned)reg;
        rawS[r0*64u + cb + m]              = dp00[reg] + bd0;
        rawS[r0*64u + cb + 16u + m]        = dp01[reg] + bd1;
        rawS[(r0+16u)*64u + cb + m]        = dp10[reg] + bd0;
        rawS[(r0+16u)*64u + cb + 16u + m]  = dp11[reg] + bd1;
      }
    }
    __syncthreads();
    {
      bf16x8 mu8 = *(const bf16x8*)(muS + (size_t)zrow*64u + zi*8u);
      f32x4 rw0 = *(const f32x4*)(rawS + (size_t)zrow*64u + zi*8u);
      f32x4 rw1 = *(const f32x4*)(rawS + (size_t)zrow*64u + zi*8u + 4u);
      float ent = 0.f, lp = 0.f;
      float zf[8];
      #pragma unroll
      for (int j=0;j<8;j++) {
        float raw = (j < 4) ? rw0[j] : rw1[j-4];
        float sp = (raw > 20.f) ? raw : __logf(1.f + __expf(raw));
        sp += 1e-4f;
        float ls = __logf(sp);
        float e = (j < 4) ? eps0[j] : eps1[j-4];
        float zv = (float)mu8[j] + sp*e;
        zf[j] = zv;
        ent += ls;
        lp  -= 0.5f*e*e + ls;
      }
      ent += 8.f*1.4189385332046727f;
      lp  -= 8.f*0.9189385332046727f;
      bf16x8 zb;
      #pragma unroll
      for (int j=0;j<8;j++) zb[j] = (bf16)zf[j];
      *(bf16x8*)(zA + ((size_t)zi*32u + zrow)*8u) = zb;
      // output stores distributed across the 16 col-WGs (2 rows each);
      // non-temporal: outputs never re-read, keep them out of L2
      if ((zrow>>1) == c) {
        float* zo = out + ((size_t)(rowG0 + zrow)*1024u + t)*64u + zi*8u;
        f32x4 o0 = {zf[0],zf[1],zf[2],zf[3]}, o1 = {zf[4],zf[5],zf[6],zf[7]};
        __builtin_nontemporal_store(o0, (f32x4*)zo);
        __builtin_nontemporal_store(o1, (f32x4*)zo + 1);
        if (t == tend - 1u)  // carry z across chunk boundary
          *(bf16x8*)(zbuf + ((size_t)(rowG0 + zrow)*64u + zi*8u)) = zb;
      }
      ent += __shfl_down(ent, 4); lp += __shfl_down(lp, 4);
      ent += __shfl_down(ent, 2); lp += __shfl_down(lp, 2);
      ent += __shfl_down(ent, 1); lp += __shfl_down(lp, 1);
      if (zi == 0u && (zrow>>1) == c) {
        __builtin_nontemporal_store(ent, &out[16777216u + (size_t)(rowG0 + zrow)*1024u + t]);
        __builtin_nontemporal_store(lp,  &out[17039360u + (size_t)(rowG0 + zrow)*1024u + t]);
      }
    }
    __syncthreads();
  }
}

// ------------------------------- host --------------------------------------
extern "C" void kernel_launch(void* const* d_in, const int* in_sizes, int n_in,
                              void* d_out, int out_size, void* d_ws, size_t ws_size,
                              hipStream_t stream)
{
  const float* x     = (const float*)d_in[0];
  const float* noise = (const float*)d_in[1];
  const float* W_x   = (const float*)d_in[2];
  const float* W_h   = (const float*)d_in[3];
  const float* bias  = (const float*)d_in[4];
  const float* W_d   = (const float*)d_in[5];
  const float* b_d   = (const float*)d_in[6];
  float* out = (float*)d_out;
  char* ws = (char*)d_ws;

  size_t off = 0;
  unsigned* bar = (unsigned*)(ws + off);  off += 262144;  // 16ch x 8rb x 2KB
  bf16* Wdf  = (bf16*)(ws + off);         off += 65536ull*2;
  bf16* Whs  = (bf16*)(ws + off);         off += 786432ull*2;
  bf16* Wxz  = (bf16*)(ws + off);         off += 98304ull*2;
  bf16* Wxx  = (bf16*)(ws + off);         off += 393216ull*2;
  bf16* hbuf = (bf16*)(ws + off);         off += 262144ull*2;
  bf16* ubuf = (bf16*)(ws + off);         off += 262144ull*2;
  bf16* zbuf = (bf16*)(ws + off);         off += 16384ull*2;
  bf16* xT   = (bf16*)(ws + off);         off += 16777216ull*2;
  bf16* xgx  = (bf16*)(ws + off);         // tlen*16*64*96 bf16 (chunked)
  size_t fixed = off;

  unsigned tlen = 1024;
  while (tlen > 64 && fixed + (size_t)tlen*196608ull > ws_size) tlen >>= 1;
  unsigned nch = 1024/tlen;

  hipMemsetAsync(bar, 0, 262144, stream);
  repack_kernel<<<5248, 256, 0, stream>>>(W_x, W_h, W_d, Whs, Wxz, Wdf, Wxx);
  xpose_kernel<<<1024, 256, 0, stream>>>(x, xT);
  hipFuncSetAttribute((const void*)rec_kernel,
                      hipFuncAttributeMaxDynamicSharedMemorySize, LDS_REC);
  for (unsigned ch = 0; ch < nch; ++ch) {
    unsigned t0 = ch*tlen;
    xgx_kernel<<<tlen*16, 256, 0, stream>>>(xT, Wxx, bias, xgx, t0);
    rec_kernel<<<NWG, 256, LDS_REC, stream>>>(Whs, Wxz, Wdf, xgx, noise, b_d,
                                              out, hbuf, ubuf, zbuf,
                                              bar + (size_t)ch*4096u, t0, tlen);
  }
}

// Round 6
// 8908.829 us; speedup vs baseline: 1.7454x; 1.0079x over previous
//
#include <hip/hip_runtime.h>
#include <stdint.h>

// ---------------------------------------------------------------------------
// RnnInferenceNetwork: GRU-variant scan, T=1024, SB=256 rows, H=512, L=64.
// 128 persistent wgs (8 row-blocks x 16 col-groups), weights in LDS/VGPRs,
// h/u exchanged through the XCD-local L2 (self-tested; LLC fallback).
// R8: BARRIER-DRAIN ELIMINATION. __syncthreads (vmcnt(0)+lgkmcnt(0) drain)
// replaced by raw s_barrier: LDS barriers wait lgkmcnt(0) only; exchange
// stores are atomic-swap-with-ack (compiler emits a counted wait on the
// returned value -> store at L2 before flag publish, unrelated loads stay in
// flight). xgx/noise for step t+1 prefetched into registers mid-step-t.
// Output stores never drained. L2 flags spread one line per WG; wave0 polls.
// ---------------------------------------------------------------------------

#define NWG  128u

typedef __bf16 bf16;
typedef __attribute__((ext_vector_type(8))) __bf16 bf16x8;
typedef __attribute__((ext_vector_type(8))) short  s16x8;
typedef __attribute__((ext_vector_type(4))) float  f32x4;
typedef __attribute__((ext_vector_type(4))) unsigned int u32x4;
typedef __attribute__((ext_vector_type(2))) unsigned long long u64x2;

__device__ __forceinline__ f32x4 mfma16(bf16x8 a, bf16x8 b, f32x4 c) {
  return __builtin_amdgcn_mfma_f32_16x16x32_bf16(
      __builtin_bit_cast(s16x8, a), __builtin_bit_cast(s16x8, b), c, 0, 0, 0);
}

// ---- sc0 load helpers: bypass L1, serviced by the XCD-local L2 ------------
__device__ __forceinline__ unsigned ld_u32_sc0(const unsigned* p) {
  unsigned v;
  asm volatile("global_load_dword %0, %1, off sc0\n\ts_waitcnt vmcnt(0)"
               : "=v"(v) : "v"(p) : "memory");
  return v;
}
__device__ __forceinline__ u32x4 ld_u128_sc0(const void* p) {
  u32x4 v;
  asm volatile("global_load_dwordx4 %0, %1, off sc0" : "=v"(v) : "v"(p));
  return v;
}
__device__ __forceinline__ void vm_wait0() {
  asm volatile("s_waitcnt vmcnt(0)" ::: "memory");
  __builtin_amdgcn_sched_barrier(0);   // keep consumers after the wait
}
// ---- LDS-only barrier: lgkmcnt(0) + raw s_barrier (NO vmem drain) ---------
__device__ __forceinline__ void bar_lds() {
  asm volatile("s_waitcnt lgkmcnt(0)" ::: "memory");
  __builtin_amdgcn_s_barrier();
}
// ---- store-with-ack: atomic swap; consuming the old value forces a counted
// vmcnt wait on THIS op only (store visible at L2/LLC), leaving prefetch
// loads and output stores in flight.
__device__ __forceinline__ void st_ack(unsigned long long* p,
                                       unsigned long long v, bool l2m) {
  unsigned long long old;
  if (l2m) old = __hip_atomic_exchange(p, v, __ATOMIC_RELAXED,
                                       __HIP_MEMORY_SCOPE_WORKGROUP);
  else     old = __hip_atomic_exchange(p, v, __ATOMIC_RELAXED,
                                       __HIP_MEMORY_SCOPE_AGENT);
  asm volatile("" :: "v"(old));
}

// --------------------------- repack weights --------------------------------
__global__ void repack_kernel(const float* __restrict__ W_x,
                              const float* __restrict__ W_h,
                              const float* __restrict__ W_d,
                              bf16* __restrict__ Whs, bf16* __restrict__ Wxz,
                              bf16* __restrict__ Wdf, bf16* __restrict__ Wxx)
{
  unsigned e = blockIdx.x*256u + threadIdx.x;
  if (e < 786432u) {
    unsigned c = e/49152u, r0 = e%49152u;
    unsigned kc = r0/3072u, r1 = r0%3072u;
    unsigned q = r1/768u, r2 = r1%768u;
    unsigned n = r2/8u, j = r2%8u;
    unsigned k = kc*32u + q*8u + j;
    unsigned colg = (n>>5)*512u + c*32u + (n&31u);
    Whs[e] = (bf16)W_h[k*1536u + colg];
  } else if (e < 884736u) {
    unsigned e1 = e - 786432u;
    unsigned c = e1/6144u, r0 = e1%6144u;
    unsigned kc = r0/3072u, r1 = r0%3072u;
    unsigned q = r1/768u, r2 = r1%768u;
    unsigned n = r2/8u, j = r2%8u;
    unsigned k = 256u + kc*32u + q*8u + j;
    unsigned colg = (n>>5)*512u + c*32u + (n&31u);
    Wxz[e1] = (bf16)W_x[k*1536u + colg];
  } else if (e < 950272u) {
    unsigned e2 = e - 884736u;
    unsigned kc = e2/4096u, r0 = e2%4096u;
    unsigned q = r0/1024u, r1 = r0%1024u;
    unsigned n = r1/8u, j = r1%8u;
    unsigned k = kc*32u + q*8u + j;
    Wdf[e2] = (bf16)W_d[k*128u + n];
  } else if (e < 1343488u) {
    unsigned e3 = e - 950272u;
    unsigned c = e3/24576u, r0 = e3%24576u;
    unsigned kc = r0/3072u, r1 = r0%3072u;
    unsigned q = r1/768u, r2 = r1%768u;
    unsigned n = r2/8u, j = r2%8u;
    unsigned k = kc*32u + q*8u + j;
    unsigned colg = (n>>5)*512u + c*32u + (n&31u);
    Wxx[e3] = (bf16)W_x[k*1536u + colg];
  }
}

// ----------------- transpose x [B][T][D] f32 -> xT [t][b][d] bf16 ----------
__global__ void xpose_kernel(const float* __restrict__ x, bf16* __restrict__ xT)
{
  unsigned t = blockIdx.x, tid = threadIdx.x;
  unsigned row = tid>>2, seg = tid&3u;
  const float* src = x + ((size_t)row*1024u + t)*256u + seg*64u;
  bf16* dst = xT + (size_t)t*16384u + row*256u + seg*64u;
  #pragma unroll
  for (int i = 0; i < 8; ++i) {
    f32x4 v0 = *(const f32x4*)(src + i*8);
    f32x4 v1 = *(const f32x4*)(src + i*8 + 4);
    bf16x8 o;
    #pragma unroll
    for (int j = 0; j < 4; ++j) { o[j] = (bf16)v0[j]; o[4+j] = (bf16)v1[j]; }
    *(bf16x8*)(dst + i*8) = o;
  }
}

// --------- xg_x precompute: xgx[lt][c][b64][n96] = x@W_x[:256]+b (bf16) ----
__global__ void __launch_bounds__(256) xgx_kernel(const bf16* __restrict__ xT,
                                                  const bf16* __restrict__ Wxx,
                                                  const float* __restrict__ bias,
                                                  bf16* __restrict__ xgx,
                                                  unsigned t0)
{
  __shared__ bf16 WxS[24576];
  __shared__ bf16 otile[6144];
  unsigned bid = blockIdx.x, lt = bid>>4, c = bid&15u, tid = threadIdx.x;
  unsigned t = t0 + lt;
  { const u32x4* s = (const u32x4*)(Wxx + (size_t)c*24576u); u32x4* d = (u32x4*)WxS;
    #pragma unroll
    for (int i=0;i<12;i++) d[tid+256u*i] = s[tid+256u*i]; }
  __syncthreads();
  unsigned wave = tid>>6, lane = tid&63u, q = lane>>4, m = lane&15u;
  f32x4 zero4 = {0.f,0.f,0.f,0.f};
  f32x4 acc[6];
  #pragma unroll
  for (int nt=0;nt<6;nt++) acc[nt] = zero4;
  const bf16* ap = xT + (size_t)t*16384u + (16u*wave + m)*256u + q*8u;
  #pragma unroll
  for (int kc=0;kc<8;kc++) {
    bf16x8 a = *(const bf16x8*)(ap + kc*32);
    #pragma unroll
    for (int nt=0;nt<6;nt++) {
      bf16x8 bb = *(const bf16x8*)(WxS + (((unsigned)kc*4u+q)*96u + (unsigned)nt*16u + m)*8u);
      acc[nt] = mfma16(a, bb, acc[nt]);
    }
  }
  #pragma unroll
  for (int nt=0;nt<6;nt++) {
    unsigned n = (unsigned)nt*16u + m;
    unsigned colg = (n>>5)*512u + c*32u + (n&31u);
    float bv = bias[colg];
    #pragma unroll
    for (int reg=0;reg<4;reg++)
      otile[(16u*wave + 4u*q + (unsigned)reg)*96u + n] = (bf16)(acc[nt][reg] + bv);
  }
  __syncthreads();
  { u32x4* d = (u32x4*)(xgx + (size_t)(lt*16u + c)*6144u);
    const u32x4* s = (const u32x4*)otile;
    #pragma unroll
    for (int i=0;i<3;i++) d[tid+256u*i] = s[tid+256u*i]; }
}

// ------------------- per-row-block barriers (16 WGs) -----------------------
// LLC variant (R4, proven) with __syncthreads drains: used ONLY pre-loop
// (self-test handshake), where drains are harmless.
__device__ __forceinline__ void rb_bar_llc(unsigned* __restrict__ flags,
                                           unsigned tid, unsigned lane,
                                           unsigned wave, unsigned c,
                                           unsigned target)
{
  __syncthreads();
  if (tid == 0)
    __hip_atomic_store(&flags[c], target, __ATOMIC_RELAXED,
                       __HIP_MEMORY_SCOPE_AGENT);
  if (wave == 0) {
    for (;;) {
      unsigned v = target;
      if (lane < 16u)
        v = __hip_atomic_load(&flags[lane], __ATOMIC_RELAXED,
                              __HIP_MEMORY_SCOPE_AGENT);
      if (__all((int)(v >= target))) break;
      __builtin_amdgcn_s_sleep(1);
    }
  }
  __syncthreads();
}

// In-loop exchange barrier: raw s_barrier (no drains -- callers ack'd their
// data stores via st_ack). l2m: flags spread one 128-B line per WG, plain
// publish, wave0 sc0-poll. Fallback: agent atomics on the LLC flag line.
__device__ __forceinline__ void xbar(unsigned* __restrict__ fl2,
                                     unsigned* __restrict__ fllc, bool l2m,
                                     unsigned tid, unsigned lane, unsigned wave,
                                     unsigned c, unsigned tl2, unsigned tllc)
{
  __builtin_amdgcn_s_barrier();   // all threads' data-store acks complete
  if (l2m) {
    if (tid == 0)
      __hip_atomic_store(&fl2[c*32u], tl2, __ATOMIC_RELAXED,
                         __HIP_MEMORY_SCOPE_WORKGROUP);
    if (wave == 0) {
      for (;;) {
        unsigned v = tl2;
        if (lane < 16u) v = ld_u32_sc0(&fl2[lane*32u]);
        if (__all((int)(v >= tl2))) break;
      }
    }
  } else {
    if (tid == 0)
      __hip_atomic_store(&fllc[c], tllc, __ATOMIC_RELAXED,
                         __HIP_MEMORY_SCOPE_AGENT);
    if (wave == 0) {
      for (;;) {
        unsigned v = tllc;
        if (lane < 16u)
          v = __hip_atomic_load(&fllc[lane], __ATOMIC_RELAXED,
                                __HIP_MEMORY_SCOPE_AGENT);
        if (__all((int)(v >= tllc))) break;
        __builtin_amdgcn_s_sleep(1);
      }
    }
  }
  __builtin_amdgcn_s_barrier();
}

// ------------------------------ recurrent kernel ---------------------------
// grid = 128: r = blockIdx%8 (row-block -> one XCD under round-robin),
// c = blockIdx/8. bar region per row-block: 1024 u32 (4 KB):
//   [0..15] LLC flags | [32..47] xcd ids | [96..111] verdicts |
//   [128..383] selftest slots | [512 + c*32] spread L2 flags
#define LDS_REC 159744
__global__ void __launch_bounds__(256, 1) rec_kernel(
    const bf16* __restrict__ Whs_g, const bf16* __restrict__ Wxz_g,
    const bf16* __restrict__ Wdf_g, const bf16* __restrict__ xgx,
    const float* __restrict__ noise, const float* __restrict__ b_d,
    float* __restrict__ out, bf16* __restrict__ hbuf, bf16* __restrict__ ubuf,
    bf16* __restrict__ zbuf, unsigned* __restrict__ bar,
    unsigned t0, unsigned tlen)
{
  extern __shared__ char smem[];
  bf16*  WhS  = (bf16*)(smem);            // 49152 el = 98304 B
  bf16*  WxzS = (bf16*)(smem + 98304);    // 6144 el = 12288 B
  bf16*  hA   = (bf16*)(smem + 110592);   // 16384 el  [kc16][q4][row32][j8]
  bf16*  zA   = (bf16*)(smem + 143360);   // 2048 el   [kc2][q4][row32][j8]
  bf16*  stg  = (bf16*)(smem + 147456);   // 1024 el   [q4][row32][j8]
  float* zgSf = (float*)(smem + 149504);  // 1024 el   [row32][col32] fp32
  bf16*  muS  = (bf16*)(smem + 147456);   // 2048 el   [row32][col64] (overlay)
  float* rawS = (float*)(smem + 151552);  // 2048 el   [row32][col64] fp32

  const unsigned tid = threadIdx.x;
  const unsigned wave = tid>>6, lane = tid&63u, q = lane>>4, m = lane&15u;
  const unsigned mt = wave&1u, gt = wave>>1;
  const unsigned r = blockIdx.x & 7u, c = blockIdx.x >> 3;
  const unsigned b0 = (r&1u)*32u;
  const unsigned rowG0 = r*32u;
  const unsigned zrow = tid>>3, zi = tid&7u;
  unsigned* rb  = bar + (size_t)r*1024u;
  unsigned* l2f = rb + 512u;

  // ---- stage resident weights ----
  { const u32x4* s = (const u32x4*)(Whs_g + (size_t)c*49152u); u32x4* d = (u32x4*)WhS;
    #pragma unroll
    for (int i=0;i<24;i++) d[tid+256u*i] = s[tid+256u*i]; }
  { const u32x4* s = (const u32x4*)(Wxz_g + (size_t)c*6144u); u32x4* d = (u32x4*)WxzS;
    #pragma unroll
    for (int i=0;i<3;i++) d[tid+256u*i] = s[tid+256u*i]; }
  // ---- W_d fragments in VGPRs ----
  bf16x8 wd[16][2];
  #pragma unroll
  for (int kc=0;kc<16;kc++) {
    #pragma unroll
    for (int nw=0;nw<2;nw++)
      wd[kc][nw] = *(const bf16x8*)(Wdf_g +
          ((((unsigned)kc*4u+q)*128u + wave*32u + (unsigned)nw*16u + m)*8u));
  }
  float bd0 = b_d[wave*32u + m], bd1 = b_d[wave*32u + 16u + m];

  // =================== R6 self-testing XCD handshake =====================
  bool l2m;
  {
    unsigned* ts = rb + 128u;
    unsigned myxcd;
    asm volatile("s_getreg_b32 %0, hwreg(HW_REG_XCC_ID)" : "=s"(myxcd));
    myxcd = (myxcd & 15u) + 1u;
    if (tid == 0)
      __hip_atomic_store(&rb[32u + c], myxcd, __ATOMIC_RELAXED,
                         __HIP_MEMORY_SCOPE_AGENT);
    rb_bar_llc(rb, tid, lane, wave, c, 1u);
    bool xcdok;
    { unsigned v = myxcd;
      if (lane < 16u)
        v = __hip_atomic_load(&rb[32u + lane], __ATOMIC_RELAXED,
                              __HIP_MEMORY_SCOPE_AGENT);
      xcdok = (bool)__all((int)(v == myxcd));
    }
    if (tid < 16u)
      __hip_atomic_store(&ts[c*16u + tid], 0xA0000000u + (c<<8) + tid,
                         __ATOMIC_RELAXED, __HIP_MEMORY_SCOPE_WORKGROUP);
    rb_bar_llc(rb, tid, lane, wave, c, 2u);
    unsigned jj = tid>>4, ii = tid&15u;
    bool okA = (ld_u32_sc0(&ts[tid]) == 0xA0000000u + (jj<<8) + ii);
    rb_bar_llc(rb, tid, lane, wave, c, 3u);
    if (tid < 16u)
      __hip_atomic_store(&ts[c*16u + tid], 0xB0000000u + (c<<8) + tid,
                         __ATOMIC_RELAXED, __HIP_MEMORY_SCOPE_WORKGROUP);
    rb_bar_llc(rb, tid, lane, wave, c, 4u);
    bool okB = (ld_u32_sc0(&ts[tid]) == 0xB0000000u + (jj<<8) + ii);
    unsigned* sc = (unsigned*)stg;
    sc[0] = 1u; __syncthreads();
    if (!(okA && okB)) sc[0] = 0u;
    __syncthreads();
    unsigned myok = (sc[0] != 0u) ? 1u : 2u;
    __syncthreads();
    if (tid == 0)
      __hip_atomic_store(&rb[96u + c], myok, __ATOMIC_RELAXED,
                         __HIP_MEMORY_SCOPE_AGENT);
    rb_bar_llc(rb, tid, lane, wave, c, 5u);
    { unsigned v = 1u;
      if (lane < 16u)
        v = __hip_atomic_load(&rb[96u + lane], __ATOMIC_RELAXED,
                              __HIP_MEMORY_SCOPE_AGENT);
      l2m = xcdok && (bool)__all((int)(v == 1u));
    }
  }

  // ---- init state ----
  float hstate[4];
  if (t0 == 0) {
    u32x4 zz = {0,0,0,0};
    u32x4* d = (u32x4*)hA;
    #pragma unroll
    for (int i=0;i<8;i++) d[tid+256u*i] = zz;
    ((u32x4*)zA)[tid] = zz;
    #pragma unroll
    for (int reg=0;reg<4;reg++) hstate[reg] = 0.f;
    __syncthreads();
  } else {
    const u32x4* s = (const u32x4*)(hbuf + ((size_t)(1u*8u + r)*16u)*1024u);
    u32x4* d = (u32x4*)hA;
    #pragma unroll
    for (int i=0;i<8;i++) d[tid+256u*i] = s[tid+256u*i];
    bf16x8 zv = *(const bf16x8*)(zbuf + ((size_t)(rowG0 + zrow)*64u + zi*8u));
    *(bf16x8*)(zA + ((size_t)zi*32u + zrow)*8u) = zv;
    __syncthreads();
    unsigned cl = gt*16u + m;
    #pragma unroll
    for (int reg=0;reg<4;reg++)
      hstate[reg] = (float)hA[((c*4u + (cl>>3))*32u + 16u*mt + 4u*q + (unsigned)reg)*8u + (cl&7u)];
  }

  const unsigned tend = t0 + tlen;
  // ---- prologue prefetch for step t0 (current-step registers) ----
  __bf16 xc1[2][4]; __bf16 xc2[4]; f32x4 ec0, ec1;
  { size_t base = ((size_t)(0u*16u + c)*64u + b0 + 16u*mt + 4u*q)*96u + m;
    #pragma unroll
    for (int nt=0;nt<2;nt++)
      #pragma unroll
      for (int reg=0;reg<4;reg++)
        xc1[nt][reg] = xgx[base + (unsigned)reg*96u + gt*32u + (unsigned)nt*16u];
    #pragma unroll
    for (int reg=0;reg<4;reg++)
      xc2[reg] = xgx[base + (unsigned)reg*96u + 64u + gt*16u];
    const f32x4* np4 = (const f32x4*)(noise + ((size_t)t0*256u + rowG0 + zrow)*64u + zi*8u);
    ec0 = np4[0]; ec1 = np4[1];
  }

  for (unsigned t = t0; t < tend; ++t) {
    unsigned par = t & 1u;
    unsigned kb = 2u*(t - t0);

    // ================= phase 1: z/r gates, u = r*h =================
    f32x4 accP0 = {0.f,0.f,0.f,0.f}, accP1 = {0.f,0.f,0.f,0.f};
    #pragma unroll
    for (int kc=0;kc<2;kc++) {
      bf16x8 a = *(const bf16x8*)(zA + (((unsigned)kc*4u+q)*32u + 16u*mt + m)*8u);
      accP0 = mfma16(a, *(const bf16x8*)(WxzS + (((unsigned)kc*4u+q)*96u + gt*32u + m)*8u), accP0);
      accP1 = mfma16(a, *(const bf16x8*)(WxzS + (((unsigned)kc*4u+q)*96u + gt*32u + 16u + m)*8u), accP1);
    }
    #pragma unroll
    for (int kc=0;kc<16;kc++) {
      bf16x8 a = *(const bf16x8*)(hA + (((unsigned)kc*4u+q)*32u + 16u*mt + m)*8u);
      accP0 = mfma16(a, *(const bf16x8*)(WhS + (((unsigned)kc*4u+q)*96u + gt*32u + m)*8u), accP0);
      accP1 = mfma16(a, *(const bf16x8*)(WhS + (((unsigned)kc*4u+q)*96u + gt*32u + 16u + m)*8u), accP1);
    }
    #pragma unroll
    for (int reg=0;reg<4;reg++) {
      unsigned rloc = 16u*mt + 4u*q + (unsigned)reg;
      float g0 = accP0[reg] + (float)xc1[0][reg];
      float g1 = accP1[reg] + (float)xc1[1][reg];
      float s0 = 1.f/(1.f + __expf(-g0));
      float s1 = 1.f/(1.f + __expf(-g1));
      if (gt == 0) {
        zgSf[rloc*32u + m]       = s0;
        zgSf[rloc*32u + 16u + m] = s1;
      } else {
        unsigned cl0 = m, cl1 = 16u + m;
        float h0 = (float)hA[((c*4u + (cl0>>3))*32u + rloc)*8u + (cl0&7u)];
        float h1 = (float)hA[((c*4u + (cl1>>3))*32u + rloc)*8u + (cl1&7u)];
        stg[((cl0>>3)*32u + rloc)*8u + (cl0&7u)] = (bf16)(s0*h0);
        stg[((cl1>>3)*32u + rloc)*8u + (cl1&7u)] = (bf16)(s1*h1);
      }
    }
    bar_lds();   // stg/zgSf visible (LDS only; no vmem drain)
    // u slice -> ubuf with per-op ack
    { size_t blk = ((size_t)(par*8u + r)*16u + c)*1024u;
      unsigned long long v = *(const unsigned long long*)(stg + (size_t)tid*4u);
      st_ack((unsigned long long*)(ubuf + blk + (size_t)tid*4u), v, l2m); }
    xbar(l2f, rb, l2m, tid, lane, wave, c, kb + 1u, kb + 6u);

    // ================= phase 2: n_cand, h_new =================
    bf16x8 ufr[16];
    if (l2m) {
      const char* ub = (const char*)ubuf + (size_t)(par*8u + r)*32768u
                       + (q*32u + 16u*mt + m)*16u;
      u32x4 tmp[16];
      #pragma unroll
      for (int kc=0;kc<16;kc++) tmp[kc] = ld_u128_sc0(ub + kc*2048);
      vm_wait0();
      #pragma unroll
      for (int kc=0;kc<16;kc++) ufr[kc] = __builtin_bit_cast(bf16x8, tmp[kc]);
    } else {
      unsigned long long* ubp = (unsigned long long*)ubuf;
      size_t b64 = ((size_t)(par*8u + r)*16u)*256u + (q*32u + 16u*mt + m)*2u;
      #pragma unroll
      for (int kc=0;kc<16;kc++) {
        unsigned long long a0 = __hip_atomic_load(ubp + b64 + (unsigned)kc*256u,
                                    __ATOMIC_RELAXED, __HIP_MEMORY_SCOPE_AGENT);
        unsigned long long a1 = __hip_atomic_load(ubp + b64 + (unsigned)kc*256u + 1u,
                                    __ATOMIC_RELAXED, __HIP_MEMORY_SCOPE_AGENT);
        u64x2 tt; tt[0] = a0; tt[1] = a1;
        ufr[kc] = __builtin_bit_cast(bf16x8, tt);
      }
    }
    // ---- prefetch step t+1 operands (plain cacheable loads; consumed next
    // iteration from registers -- latency fully off the critical path) ----
    __bf16 xn1[2][4]; __bf16 xn2[4]; f32x4 en0, en1;
    { unsigned tn = (t + 1u < tend) ? (t + 1u) : t;
      size_t base = ((size_t)((tn - t0)*16u + c)*64u + b0 + 16u*mt + 4u*q)*96u + m;
      #pragma unroll
      for (int nt=0;nt<2;nt++)
        #pragma unroll
        for (int reg=0;reg<4;reg++)
          xn1[nt][reg] = xgx[base + (unsigned)reg*96u + gt*32u + (unsigned)nt*16u];
      #pragma unroll
      for (int reg=0;reg<4;reg++)
        xn2[reg] = xgx[base + (unsigned)reg*96u + 64u + gt*16u];
      const f32x4* np4 = (const f32x4*)(noise + ((size_t)tn*256u + rowG0 + zrow)*64u + zi*8u);
      en0 = np4[0]; en1 = np4[1];
    }
    // n preact = xg_n + z_prev@W_x[D:,2H:] + (r*h)@W_h[:,2H:]
    f32x4 accNa = {0.f,0.f,0.f,0.f}, accNb = {0.f,0.f,0.f,0.f};
    #pragma unroll
    for (int kc=0;kc<2;kc++) {
      bf16x8 a = *(const bf16x8*)(zA + (((unsigned)kc*4u+q)*32u + 16u*mt + m)*8u);
      accNa = mfma16(a, *(const bf16x8*)(WxzS + (((unsigned)kc*4u+q)*96u + 64u + gt*16u + m)*8u), accNa);
    }
    #pragma unroll
    for (int kc=0;kc<16;kc++) {
      f32x4& acc = (kc & 1) ? accNb : accNa;
      acc = mfma16(ufr[kc], *(const bf16x8*)(WhS + (((unsigned)kc*4u+q)*96u + 64u + gt*16u + m)*8u), acc);
    }
    { unsigned colL2 = gt*16u + m;
      #pragma unroll
      for (int reg=0;reg<4;reg++) {
        unsigned rloc = 16u*mt + 4u*q + (unsigned)reg;
        float zg = zgSf[rloc*32u + colL2];
        float pre = accNa[reg] + accNb[reg] + (float)xc2[reg];
        float e2 = __expf(2.f*pre);
        float nc = 1.f - 2.f/(e2 + 1.f);
        float hn = (1.f - zg)*nc + zg*hstate[reg];
        hstate[reg] = hn;
        stg[((colL2>>3)*32u + rloc)*8u + (colL2&7u)] = (bf16)hn;
      }
    }
    bar_lds();   // stg visible
    { size_t blk = ((size_t)(par*8u + r)*16u + c)*1024u;
      unsigned long long v = *(const unsigned long long*)(stg + (size_t)tid*4u);
      st_ack((unsigned long long*)(hbuf + blk + (size_t)tid*4u), v, l2m); }
    xbar(l2f, rb, l2m, tid, lane, wave, c, kb + 2u, kb + 7u);
    // gather full h_new for own rows into hA
    if (l2m) {
      const char* hb = (const char*)hbuf + (size_t)(par*8u + r)*32768u
                       + (size_t)tid*16u;
      u32x4 g[8];
      #pragma unroll
      for (int i=0;i<8;i++) g[i] = ld_u128_sc0(hb + i*4096);
      vm_wait0();
      #pragma unroll
      for (int i=0;i<8;i++) ((u32x4*)hA)[tid + 256u*i] = g[i];
    } else {
      unsigned long long* s = (unsigned long long*)(hbuf + ((size_t)(par*8u + r)*16u)*1024u);
      unsigned long long* d = (unsigned long long*)hA;
      unsigned long long gtmp[16];
      #pragma unroll
      for (int i=0;i<16;i++)
        gtmp[i] = __hip_atomic_load(s + tid + 256u*i,
                                    __ATOMIC_RELAXED, __HIP_MEMORY_SCOPE_AGENT);
      #pragma unroll
      for (int i=0;i<16;i++) d[tid + 256u*i] = gtmp[i];
    }
    bar_lds();   // hA visible

    // ================= phase 3: dp = h_new@W_d, sample, outputs =========
    f32x4 dp00={0.f,0.f,0.f,0.f}, dp01={0.f,0.f,0.f,0.f};
    f32x4 dp10={0.f,0.f,0.f,0.f}, dp11={0.f,0.f,0.f,0.f};
    #pragma unroll
    for (int kc=0;kc<16;kc++) {
      bf16x8 a0 = *(const bf16x8*)(hA + (((unsigned)kc*4u+q)*32u + m)*8u);
      bf16x8 a1 = *(const bf16x8*)(hA + (((unsigned)kc*4u+q)*32u + 16u + m)*8u);
      dp00 = mfma16(a0, wd[kc][0], dp00);
      dp01 = mfma16(a0, wd[kc][1], dp01);
      dp10 = mfma16(a1, wd[kc][0], dp10);
      dp11 = mfma16(a1, wd[kc][1], dp11);
    }
    if (wave < 2u) {
      #pragma unroll
      for (int reg=0;reg<4;reg++) {
        unsigned r0 = 4u*q + (unsigned)reg;
        muS[r0*64u + wave*32u + m]              = (bf16)(dp00[reg] + bd0);
        muS[r0*64u + wave*32u + 16u + m]        = (bf16)(dp01[reg] + bd1);
        muS[(r0+16u)*64u + wave*32u + m]        = (bf16)(dp10[reg] + bd0);
        muS[(r0+16u)*64u + wave*32u + 16u + m]  = (bf16)(dp11[reg] + bd1);
      }
    } else {
      unsigned cb = (wave - 2u)*32u;
      #pragma unroll
      for (int reg=0;reg<4;reg++) {
        unsigned r0 = 4u*q + (unsigned)reg;
        rawS[r0*64u + cb + m]              = dp00[reg] + bd0;
        rawS[r0*64u + cb + 16u + m]        = dp01[reg] + bd1;
        rawS[(r0+16u)*64u + cb + m]        = dp10[reg] + bd0;
        rawS[(r0+16u)*64u + cb + 16u + m]  = dp11[reg] + bd1;
      }
    }
    bar_lds();   // muS/rawS visible
    {
      bf16x8 mu8 = *(const bf16x8*)(muS + (size_t)zrow*64u + zi*8u);
      f32x4 rw0 = *(const f32x4*)(rawS + (size_t)zrow*64u + zi*8u);
      f32x4 rw1 = *(const f32x4*)(rawS + (size_t)zrow*64u + zi*8u + 4u);
      float ent = 0.f, lp = 0.f;
      float zf[8];
      #pragma unroll
      for (int j=0;j<8;j++) {
        float raw = (j < 4) ? rw0[j] : rw1[j-4];
        float sp = (raw > 20.f) ? raw : __logf(1.f + __expf(raw));
        sp += 1e-4f;
        float ls = __logf(sp);
        float e = (j < 4) ? ec0[j] : ec1[j-4];
        float zv = (float)mu8[j] + sp*e;
        zf[j] = zv;
        ent += ls;
        lp  -= 0.5f*e*e + ls;
      }
      ent += 8.f*1.4189385332046727f;
      lp  -= 8.f*0.9189385332046727f;
      bf16x8 zb;
      #pragma unroll
      for (int j=0;j<8;j++) zb[j] = (bf16)zf[j];
      *(bf16x8*)(zA + ((size_t)zi*32u + zrow)*8u) = zb;
      // distributed output stores (2 rows per col-WG); nt, never drained
      if ((zrow>>1) == c) {
        float* zo = out + ((size_t)(rowG0 + zrow)*1024u + t)*64u + zi*8u;
        f32x4 o0 = {zf[0],zf[1],zf[2],zf[3]}, o1 = {zf[4],zf[5],zf[6],zf[7]};
        __builtin_nontemporal_store(o0, (f32x4*)zo);
        __builtin_nontemporal_store(o1, (f32x4*)zo + 1);
        if (t == tend - 1u)
          *(bf16x8*)(zbuf + ((size_t)(rowG0 + zrow)*64u + zi*8u)) = zb;
      }
      ent += __shfl_down(ent, 4); lp += __shfl_down(lp, 4);
      ent += __shfl_down(ent, 2); lp += __shfl_down(lp, 2);
      ent += __shfl_down(ent, 1); lp += __shfl_down(lp, 1);
      if (zi == 0u && (zrow>>1) == c) {
        __builtin_nontemporal_store(ent, &out[16777216u + (size_t)(rowG0 + zrow)*1024u + t]);
        __builtin_nontemporal_store(lp,  &out[17039360u + (size_t)(rowG0 + zrow)*1024u + t]);
      }
    }
    bar_lds();   // zA visible for next P1; muS/rawS region free
    // rotate prefetch -> current
    #pragma unroll
    for (int nt=0;nt<2;nt++)
      #pragma unroll
      for (int reg=0;reg<4;reg++) xc1[nt][reg] = xn1[nt][reg];
    #pragma unroll
    for (int reg=0;reg<4;reg++) xc2[reg] = xn2[reg];
    ec0 = en0; ec1 = en1;
  }
}

// ------------------------------- host --------------------------------------
extern "C" void kernel_launch(void* const* d_in, const int* in_sizes, int n_in,
                              void* d_out, int out_size, void* d_ws, size_t ws_size,
                              hipStream_t stream)
{
  const float* x     = (const float*)d_in[0];
  const float* noise = (const float*)d_in[1];
  const float* W_x   = (const float*)d_in[2];
  const float* W_h   = (const float*)d_in[3];
  const float* bias  = (const float*)d_in[4];
  const float* W_d   = (const float*)d_in[5];
  const float* b_d   = (const float*)d_in[6];
  float* out = (float*)d_out;
  char* ws = (char*)d_ws;

  size_t off = 0;
  unsigned* bar = (unsigned*)(ws + off);  off += 524288;  // 16ch x 8rb x 4KB
  bf16* Wdf  = (bf16*)(ws + off);         off += 65536ull*2;
  bf16* Whs  = (bf16*)(ws + off);         off += 786432ull*2;
  bf16* Wxz  = (bf16*)(ws + off);         off += 98304ull*2;
  bf16* Wxx  = (bf16*)(ws + off);         off += 393216ull*2;
  bf16* hbuf = (bf16*)(ws + off);         off += 262144ull*2;
  bf16* ubuf = (bf16*)(ws + off);         off += 262144ull*2;
  bf16* zbuf = (bf16*)(ws + off);         off += 16384ull*2;
  bf16* xT   = (bf16*)(ws + off);         off += 16777216ull*2;
  bf16* xgx  = (bf16*)(ws + off);         // tlen*16*64*96 bf16 (chunked)
  size_t fixed = off;

  unsigned tlen = 1024;
  while (tlen > 64 && fixed + (size_t)tlen*196608ull > ws_size) tlen >>= 1;
  unsigned nch = 1024/tlen;

  hipMemsetAsync(bar, 0, 524288, stream);
  repack_kernel<<<5248, 256, 0, stream>>>(W_x, W_h, W_d, Whs, Wxz, Wdf, Wxx);
  xpose_kernel<<<1024, 256, 0, stream>>>(x, xT);
  hipFuncSetAttribute((const void*)rec_kernel,
                      hipFuncAttributeMaxDynamicSharedMemorySize, LDS_REC);
  for (unsigned ch = 0; ch < nch; ++ch) {
    unsigned t0 = ch*tlen;
    xgx_kernel<<<tlen*16, 256, 0, stream>>>(xT, Wxx, bias, xgx, t0);
    rec_kernel<<<NWG, 256, LDS_REC, stream>>>(Whs, Wxz, Wdf, xgx, noise, b_d,
                                              out, hbuf, ubuf, zbuf,
                                              bar + (size_t)ch*8192u, t0, tlen);
  }
}